// Round 3
// baseline (1700.409 us; speedup 1.0000x reference)
//
#include <hip/hip_runtime.h>
#include <hip/hip_bf16.h>

typedef __hip_bfloat16 bf16;
typedef __attribute__((ext_vector_type(8))) __bf16 bf16x8;
typedef __attribute__((ext_vector_type(4))) float f32x4;

#define B_   64
#define NPG_ 20
#define H_   512
#define TD_  256
#define NF_  128
#define NL_  6
#define A_   100
#define N_   (B_ * NPG_)            // 1280
#define E_   (B_ * NPG_ * (NPG_-1)) // 24320
#define EIN_ 2313

__device__ __forceinline__ float bf2f(bf16 x) { return __bfloat162float(x); }
__device__ __forceinline__ bf16  f2bf(float x) { return __float2bfloat16(x); }
__device__ __forceinline__ float siluf(float x) { return x / (1.0f + expf(-x)); }
// dual-dtype load: isb=1 -> bf16, else float32
__device__ __forceinline__ float ldf(const void* p, size_t i, int isb) {
    return isb ? bf2f(((const bf16*)p)[i]) : ((const float*)p)[i];
}

// ---------------------------------------------------------------- dtype detect: t is uniform [0,1)
__global__ void detect_dtype(const unsigned int* __restrict__ tw, int* __restrict__ flag) {
    if (threadIdx.x != 0) return;
    int cnt = 0;
    for (int i = 0; i < 32; i++) {
        unsigned b1 = (tw[i] >> 8) & 0xFF;          // bf16: sign+exp byte of elem0; f32: mantissa bits
        if (b1 >= 0x20 && b1 < 0x40) cnt++;
    }
    *flag = (cnt >= 16) ? 1 : 0;
}

__global__ void ws_sentinel(bf16* out) { if (threadIdx.x == 0) out[0] = f2bf(1000.0f); }

// ---------------------------------------------------------------- prep: lattice -> ltl (B,3,3)
__global__ void prep_graph(const void* __restrict__ latp, float* __restrict__ ltl,
                           const int* __restrict__ flag) {
    int b = threadIdx.x;
    if (b >= B_) return;
    int isb = *flag;
    const float LM[3] = {1.575442910194397f, 1.7017393112182617f, 1.9781638383865356f};
    const float LS[3] = {0.24437622725963593f, 0.26526379585266113f, 0.3535512685775757f};
    float lp[6];
    for (int i = 0; i < 6; i++) lp[i] = ldf(latp, b*6 + i, isb);
    float len[3], c[3], s[3];
    for (int i = 0; i < 3; i++) len[i] = expf(lp[i] * LS[i] + LM[i]);
    for (int i = 0; i < 3; i++) {
        float sig = 1.0f / (1.0f + expf(-lp[3+i]));
        float deg = 59.9f + 60.2f * sig;
        float a = deg * 0.017453292519943295f;
        c[i] = cosf(a); s[i] = sinf(a);
    }
    float val = (c[0]*c[1] - c[2]) / (s[0]*s[1]);
    val = fminf(1.0f, fmaxf(-1.0f, val));
    float gs = acosf(val);
    float L[3][3];
    L[0][0] = len[0]*s[1]; L[0][1] = 0.0f;               L[0][2] = len[0]*c[1];
    L[1][0] = -len[1]*s[0]*cosf(gs); L[1][1] = len[1]*s[0]*sinf(gs); L[1][2] = len[1]*c[0];
    L[2][0] = 0.0f; L[2][1] = 0.0f; L[2][2] = len[2];
    for (int i = 0; i < 3; i++)
        for (int k = 0; k < 3; k++)
            ltl[b*9 + i*3 + k] = L[i][0]*L[k][0] + L[i][1]*L[k][1] + L[i][2]*L[k][2];
}

// ---------------------------------------------------------------- prep: q[j] = sum_d W_time[d]*W_latent[512+d][j]
__global__ __launch_bounds__(512) void prep_q(const void* __restrict__ W_time,
                                              const void* __restrict__ W_latent,
                                              float* __restrict__ q,
                                              const int* __restrict__ flag) {
    int j = threadIdx.x;
    int isb = *flag;
    float s = 0.0f;
    for (int d = 0; d < TD_; d++)
        s += ldf(W_time, d, isb) * ldf(W_latent, (size_t)(H_ + d)*H_ + j, isb);
    q[j] = s;
}

// ---------------------------------------------------------------- prep: cbias[l][b][j] = be1 + W_numatom[l][na]@We1_na
__global__ __launch_bounds__(512) void prep_cbias(const void* __restrict__ W_numatom,
                                                  const void* __restrict__ We1,
                                                  const void* __restrict__ be1,
                                                  const int* __restrict__ num_atoms,
                                                  float* __restrict__ cbias,
                                                  const int* __restrict__ flag) {
    int l = blockIdx.x, b = blockIdx.y, j = threadIdx.x;
    int isb = *flag;
    int na = num_atoms[b] - 1;
    size_t wn = ((size_t)l*A_ + na)*H_;
    size_t w1 = ((size_t)l*EIN_ + 1801)*H_ + j;
    float s = ldf(be1, l*H_ + j, isb);
    for (int k = 0; k < H_; k++) s += ldf(W_numatom, wn + k, isb) * ldf(We1, w1 + (size_t)k*H_, isb);
    cbias[((size_t)l*B_ + b)*H_ + j] = s;
}

// ---------------------------------------------------------------- per-layer weight transpose (Bt = N x K)
__global__ __launch_bounds__(256) void transpose_layer(
    const void* __restrict__ We1p, const void* __restrict__ We2p,
    const void* __restrict__ Wn1p, const void* __restrict__ Wn2p, size_t l,
    bf16* __restrict__ WtAB, bf16* __restrict__ Wtf, bf16* __restrict__ Wte2,
    bf16* __restrict__ Wtn1, bf16* __restrict__ Wtn2,
    const int* __restrict__ flag) {
    __shared__ bf16 tile[32][33];
    int which = blockIdx.z;
    int isb = *flag;
    const void* src; size_t off; bf16* dst; int R;
    switch (which) {
        case 0:  src = We1p; off = (l*EIN_ + 3)*512;    dst = WtAB;            R = 512;  break;
        case 1:  src = We1p; off = (l*EIN_ + 515)*512;  dst = WtAB + 512*512;  R = 512;  break;
        case 2:  src = We1p; off = (l*EIN_ + 1033)*512; dst = Wtf;             R = 768;  break;
        case 3:  src = We2p; off = l*512*512;           dst = Wte2;            R = 512;  break;
        case 4:  src = Wn1p; off = l*1024*512;          dst = Wtn1;            R = 1024; break;
        default: src = Wn2p; off = l*512*512;           dst = Wtn2;            R = 512;  break;
    }
    int r0 = blockIdx.y * 32, c0 = blockIdx.x * 32;
    if (r0 >= R) return;
    #pragma unroll
    for (int i = 0; i < 32; i += 8)
        tile[threadIdx.y + i][threadIdx.x] =
            f2bf(ldf(src, off + (size_t)(r0 + threadIdx.y + i)*512 + c0 + threadIdx.x, isb));
    __syncthreads();
    #pragma unroll
    for (int i = 0; i < 32; i += 8)
        dst[(size_t)(c0 + threadIdx.y + i)*R + r0 + threadIdx.x] = tile[threadIdx.x][threadIdx.y + i];
}

// ---------------------------------------------------------------- node embedding: h = W_node[at] @ W_latent_top + t*q
__global__ __launch_bounds__(512) void node_embed(const void* __restrict__ W_node,
                                                  const void* __restrict__ W_latent,
                                                  const float* __restrict__ q,
                                                  const void* __restrict__ t,
                                                  const int* __restrict__ atom_types,
                                                  const int* __restrict__ node2graph,
                                                  float* __restrict__ h,
                                                  const int* __restrict__ flag) {
    int i = blockIdx.x, j = threadIdx.x;
    int isb = *flag;
    int at = atom_types[i] - 1; if (at < 0) at = 0;
    float tv = ldf(t, node2graph[i], isb);
    size_t wrow = (size_t)at * H_;
    float s = 0.0f;
    for (int k = 0; k < H_; k++)
        s += ldf(W_node, wrow + k, isb) * ldf(W_latent, (size_t)k*H_ + j, isb);
    h[(size_t)i*H_ + j] = s + tv * q[j];
}

// ---------------------------------------------------------------- edge prep: frac_diff -> femb(bf16) + unit_dots(f32)
__global__ __launch_bounds__(384) void edge_prep(const void* __restrict__ frac,
                                                 const int* __restrict__ edge_index,
                                                 const int* __restrict__ e2g,
                                                 const float* __restrict__ ltl,
                                                 float* __restrict__ ud,
                                                 bf16* __restrict__ femb,
                                                 const int* __restrict__ flag) {
    const float TWO_PI_F = 6.283185307179586f;
    int e = blockIdx.x;
    int isb = *flag;
    int src = edge_index[e], dst = edge_index[E_ + e];
    int tid = threadIdx.x;
    int d = tid >> 7, k = tid & 127;
    float x = ldf(frac, src*3 + d, isb), y = ldf(frac, dst*3 + d, isb);
    float z = TWO_PI_F * (y - x);
    float fd = atan2f(sinf(z), cosf(z)) / TWO_PI_F;
    float arg = fd * (TWO_PI_F * (float)k);
    float sv, cv;
    sincosf(arg, &sv, &cv);
    femb[(size_t)e*768 + d*NF_ + k]       = f2bf(sv);
    femb[(size_t)e*768 + 384 + d*NF_ + k] = f2bf(cv);
    if (tid < 3) {
        int g = e2g[e];
        float f3[3];
        for (int dd = 0; dd < 3; dd++) {
            float xx = ldf(frac, src*3 + dd, isb), yy = ldf(frac, dst*3 + dd, isb);
            float zz = TWO_PI_F * (yy - xx);
            f3[dd] = atan2f(sinf(zz), cosf(zz)) / TWO_PI_F;
        }
        float dots[3];
        for (int i = 0; i < 3; i++)
            dots[i] = ltl[g*9 + i*3 + 0]*f3[0] + ltl[g*9 + i*3 + 1]*f3[1] + ltl[g*9 + i*3 + 2]*f3[2];
        float nrm = sqrtf(dots[0]*dots[0] + dots[1]*dots[1] + dots[2]*dots[2]);
        ud[e*3 + tid] = dots[tid] / (nrm + 1e-12f);
    }
}

// ---------------------------------------------------------------- layernorm over H=512, block per node
__device__ __forceinline__ float block_sum_256(float v, float* red) {
    for (int o = 32; o; o >>= 1) v += __shfl_down(v, o);
    int w = threadIdx.x >> 6, lane = threadIdx.x & 63;
    if (lane == 0) red[w] = v;
    __syncthreads();
    float s = red[0] + red[1] + red[2] + red[3];
    __syncthreads();
    return s;
}

__global__ __launch_bounds__(256) void ln_kernel(const float* __restrict__ x,
                                                 const void* __restrict__ gamma,
                                                 const void* __restrict__ beta, size_t goff,
                                                 bf16* __restrict__ out,
                                                 bf16* __restrict__ cat,
                                                 const int* __restrict__ flag) {
    __shared__ float red[4];
    size_t n = blockIdx.x;
    int tid = threadIdx.x;
    int isb = *flag;
    const float* xr = x + n*H_;
    float v0 = xr[tid], v1 = xr[tid + 256];
    float mu = block_sum_256(v0 + v1, red) * (1.0f/512.0f);
    float d0 = v0 - mu, d1 = v1 - mu;
    float var = block_sum_256(d0*d0 + d1*d1, red) * (1.0f/512.0f);
    float rs = 1.0f / sqrtf(var + 1e-5f);
    bf16 o0 = f2bf(d0*rs*ldf(gamma, goff + tid, isb)       + ldf(beta, goff + tid, isb));
    bf16 o1 = f2bf(d1*rs*ldf(gamma, goff + tid + 256, isb) + ldf(beta, goff + tid + 256, isb));
    out[n*H_ + tid] = o0; out[n*H_ + 256 + tid] = o1;
    if (cat) { cat[n*1024 + tid] = o0; cat[n*1024 + 256 + tid] = o1; }
}

// ---------------------------------------------------------------- bf16 MFMA GEMM: C(MxN) = A(MxK) @ Bt(NxK)^T
// EPI: 0 = store bf16, 1 = silu -> bf16, 2 = resid(f32) += silu
template<int EPI>
__global__ __launch_bounds__(256) void gemm_bt(const bf16* __restrict__ A,
                                               const bf16* __restrict__ Bt,
                                               const void* __restrict__ bias, size_t boff,
                                               bf16* __restrict__ Cb,
                                               float* __restrict__ Cf,
                                               int K, int N,
                                               const int* __restrict__ flag) {
    __shared__ __align__(16) bf16 As[128*32];
    __shared__ __align__(16) bf16 Bs[128*32];
    const int tid = threadIdx.x;
    const int wave = tid >> 6, lane = tid & 63;
    const int lrow = lane & 15, lq = lane >> 4;
    const size_t m0 = (size_t)blockIdx.x * 128;
    const int n0 = blockIdx.y * 128;
    const int wm = (wave >> 1) * 64, wn = (wave & 1) * 64;
    const int srow = tid >> 2;
    const int scol = (tid & 3) * 8;
    f32x4 acc[4][4] = {};

    for (int k0 = 0; k0 < K; k0 += 32) {
        uint4 a0 = *(const uint4*)(A  + (m0 + srow) * K + k0 + scol);
        uint4 a1 = *(const uint4*)(A  + (m0 + 64 + srow) * K + k0 + scol);
        uint4 b0 = *(const uint4*)(Bt + (size_t)(n0 + srow) * K + k0 + scol);
        uint4 b1 = *(const uint4*)(Bt + (size_t)(n0 + 64 + srow) * K + k0 + scol);
        if (k0) __syncthreads();
        *(uint4*)(As + srow*32 + scol)        = a0;
        *(uint4*)(As + (64 + srow)*32 + scol) = a1;
        *(uint4*)(Bs + srow*32 + scol)        = b0;
        *(uint4*)(Bs + (64 + srow)*32 + scol) = b1;
        __syncthreads();
        bf16x8 af[4], bfr[4];
        #pragma unroll
        for (int mt = 0; mt < 4; mt++)
            af[mt] = *(const bf16x8*)(As + (wm + mt*16 + lrow)*32 + lq*8);
        #pragma unroll
        for (int nt = 0; nt < 4; nt++)
            bfr[nt] = *(const bf16x8*)(Bs + (wn + nt*16 + lrow)*32 + lq*8);
        #pragma unroll
        for (int mt = 0; mt < 4; mt++)
            #pragma unroll
            for (int nt = 0; nt < 4; nt++)
                acc[mt][nt] = __builtin_amdgcn_mfma_f32_16x16x32_bf16(af[mt], bfr[nt], acc[mt][nt], 0, 0, 0);
    }
    int isb = bias ? *flag : 0;
    #pragma unroll
    for (int mt = 0; mt < 4; mt++)
        #pragma unroll
        for (int nt = 0; nt < 4; nt++) {
            int col = n0 + wn + nt*16 + lrow;
            float bv = bias ? ldf(bias, boff + col, isb) : 0.0f;
            #pragma unroll
            for (int r = 0; r < 4; r++) {
                size_t row = m0 + wm + mt*16 + lq*4 + r;
                float x = acc[mt][nt][r] + bv;
                if (EPI == 0)      Cb[row*N + col] = f2bf(x);
                else if (EPI == 1) Cb[row*N + col] = f2bf(siluf(x));
                else               Cf[row*N + col] += siluf(x);
            }
        }
}

// ---------------------------------------------------------------- e1 = silu(fembW + hnA[src] + hnB[dst] + geo + cbias)
__global__ __launch_bounds__(256) void e1_assemble(const bf16* __restrict__ fembW,
                                                   const bf16* __restrict__ hnAB,
                                                   const float* __restrict__ ud,
                                                   const void* __restrict__ latp,
                                                   const float* __restrict__ cbias_l,
                                                   const void* __restrict__ We1, size_t l,
                                                   const int* __restrict__ edge_index,
                                                   const int* __restrict__ e2g,
                                                   bf16* __restrict__ e1,
                                                   const int* __restrict__ flag) {
    int e = blockIdx.x;
    int isb = *flag;
    int src = edge_index[e], dst = edge_index[E_ + e];
    int g = e2g[e];
    float u0 = ud[e*3], u1 = ud[e*3 + 1], u2 = ud[e*3 + 2];
    float la[6];
    #pragma unroll
    for (int i = 0; i < 6; i++) la[i] = ldf(latp, g*6 + i, isb);
    size_t wbase = l*EIN_*512;
    #pragma unroll
    for (int jj = 0; jj < 2; jj++) {
        int j = threadIdx.x + jj*256;
        float s = bf2f(fembW[(size_t)e*H_ + j])
                + bf2f(hnAB[(size_t)src*1024 + j])
                + bf2f(hnAB[(size_t)dst*1024 + 512 + j])
                + cbias_l[(size_t)g*H_ + j];
        s += u0*ldf(We1, wbase + j, isb)
           + u1*ldf(We1, wbase + 512 + j, isb)
           + u2*ldf(We1, wbase + 1024 + j, isb);
        #pragma unroll
        for (int i = 0; i < 6; i++) s += la[i]*ldf(We1, wbase + (size_t)(1027 + i)*512 + j, isb);
        e1[(size_t)e*H_ + j] = f2bf(siluf(s));
    }
}

// ---------------------------------------------------------------- agg: mean over each node's 19 contiguous edges
__global__ __launch_bounds__(256) void seg_mean(const bf16* __restrict__ e2,
                                                bf16* __restrict__ cat) {
    int n = blockIdx.x;
    #pragma unroll
    for (int jj = 0; jj < 2; jj++) {
        int j = threadIdx.x + jj*256;
        const bf16* base = e2 + (size_t)n*19*H_ + j;
        float s = 0.0f;
        #pragma unroll
        for (int i = 0; i < 19; i++) s += bf2f(base[(size_t)i*H_]);
        cat[(size_t)n*1024 + 512 + j] = f2bf(s / 19.0f);
    }
}

// ---------------------------------------------------------------- final heads (output in detected dtype)
__global__ void pos_out(const bf16* __restrict__ hln, const void* __restrict__ W_coord,
                        void* __restrict__ out, const int* __restrict__ flag) {
    int idx = blockIdx.x*256 + threadIdx.x;
    if (idx >= N_*3) return;
    int isb = *flag;
    int n = idx / 3, c = idx - n*3;
    float s = 0.0f;
    for (int k = 0; k < H_; k++)
        s += bf2f(hln[(size_t)n*H_ + k]) * ldf(W_coord, k*3 + c, isb);
    if (isb) ((bf16*)out)[idx] = f2bf(s);
    else     ((float*)out)[idx] = s;
}

__global__ __launch_bounds__(512) void cell_out(const bf16* __restrict__ hln,
                                                const void* __restrict__ W_latout,
                                                const void* __restrict__ b_latout,
                                                const int* __restrict__ num_atoms,
                                                void* __restrict__ out,
                                                const int* __restrict__ flag) {
    __shared__ float red[8*6];
    int b = blockIdx.x, j = threadIdx.x;
    int isb = *flag;
    float s = 0.0f;
    for (int i = 0; i < NPG_; i++) s += bf2f(hln[(size_t)(b*NPG_ + i)*H_ + j]);
    float m = s / (float)num_atoms[b];
    float p[6];
    #pragma unroll
    for (int c = 0; c < 6; c++)
        p[c] = m * ldf(W_latout, j*6 + c, isb) + s * ldf(W_latout, (512 + j)*6 + c, isb);
    int w = j >> 6, lane = j & 63;
    #pragma unroll
    for (int c = 0; c < 6; c++) {
        float v = p[c];
        for (int o = 32; o; o >>= 1) v += __shfl_down(v, o);
        if (lane == 0) red[w*6 + c] = v;
    }
    __syncthreads();
    if (j < 6) {
        float v = 0.0f;
        for (int w2 = 0; w2 < 8; w2++) v += red[w2*6 + j];
        float r = v + ldf(b_latout, j, isb);
        if (isb) ((bf16*)out)[N_*3 + b*6 + j] = f2bf(r);
        else     ((float*)out)[N_*3 + b*6 + j] = r;
    }
}

// ================================================================ host
extern "C" void kernel_launch(void* const* d_in, const int* in_sizes, int n_in,
                              void* d_out, int out_size, void* d_ws, size_t ws_size,
                              hipStream_t stream) {
    const void* t          = d_in[0];
    const void* frac       = d_in[1];
    const void* latp       = d_in[2];
    const int*  atom_types = (const int*)d_in[3];
    const int*  num_atoms  = (const int*)d_in[4];
    const int*  node2graph = (const int*)d_in[5];
    const int*  edge_index = (const int*)d_in[6];
    const int*  e2g        = (const int*)d_in[7];
    const void* W_node     = d_in[8];
    const void* W_time     = d_in[9];
    const void* W_latent   = d_in[10];
    const void* ln_gamma   = d_in[11];
    const void* ln_beta    = d_in[12];
    const void* We1        = d_in[13];
    const void* be1        = d_in[14];
    const void* We2        = d_in[15];
    const void* be2        = d_in[16];
    const void* Wn1        = d_in[17];
    const void* bn1        = d_in[18];
    const void* Wn2        = d_in[19];
    const void* bn2        = d_in[20];
    const void* W_numatom  = d_in[21];
    const void* fln_gamma  = d_in[22];
    const void* fln_beta   = d_in[23];
    const void* W_coord    = d_in[24];
    const void* W_latout   = d_in[25];
    const void* b_latout   = d_in[26];

    // workspace carve (~102.7 MB)
    char* p = (char*)d_ws;
    auto alloc = [&](size_t bytes) { char* r = p; p += (bytes + 255) & ~(size_t)255; return r; };
    int*   flag  = (int*)alloc(4);
    float* ltl   = (float*)alloc((size_t)B_*9*4);
    float* q     = (float*)alloc((size_t)H_*4);
    float* cbias = (float*)alloc((size_t)NL_*B_*H_*4);
    float* h     = (float*)alloc((size_t)N_*H_*4);
    float* ud    = (float*)alloc((size_t)E_*3*4);
    bf16* hn    = (bf16*)alloc((size_t)N_*H_*2);
    bf16* hnAB  = (bf16*)alloc((size_t)N_*1024*2);
    bf16* femb  = (bf16*)alloc((size_t)E_*768*2);
    bf16* fembW = (bf16*)alloc((size_t)E_*H_*2);   // reused as e2 (dead after e1_assemble)
    bf16* e1    = (bf16*)alloc((size_t)E_*H_*2);
    bf16* cat   = (bf16*)alloc((size_t)N_*1024*2);
    bf16* n1s   = (bf16*)alloc((size_t)N_*H_*2);
    bf16* WtAB  = (bf16*)alloc((size_t)1024*512*2);
    bf16* Wtf   = (bf16*)alloc((size_t)512*768*2);
    bf16* Wte2  = (bf16*)alloc((size_t)512*512*2);
    bf16* Wtn1  = (bf16*)alloc((size_t)512*1024*2);
    bf16* Wtn2  = (bf16*)alloc((size_t)512*512*2);
    bf16* e2    = fembW;
    bf16* hln   = hn;

    if ((size_t)(p - (char*)d_ws) > ws_size) {
        ws_sentinel<<<1, 64, 0, stream>>>((bf16*)d_out);
        return;
    }

    // ---- prep
    detect_dtype<<<1, 64, 0, stream>>>((const unsigned int*)t, flag);
    prep_graph<<<1, 64, 0, stream>>>(latp, ltl, flag);
    prep_q<<<1, 512, 0, stream>>>(W_time, W_latent, q, flag);
    prep_cbias<<<dim3(NL_, B_), 512, 0, stream>>>(W_numatom, We1, be1, num_atoms, cbias, flag);
    node_embed<<<N_, 512, 0, stream>>>(W_node, W_latent, q, t, atom_types, node2graph, h, flag);
    edge_prep<<<E_, 384, 0, stream>>>(frac, edge_index, e2g, ltl, ud, femb, flag);

    // ---- layers
    for (size_t l = 0; l < NL_; l++) {
        transpose_layer<<<dim3(16, 32, 6), dim3(32, 8), 0, stream>>>(
            We1, We2, Wn1, Wn2, l, WtAB, Wtf, Wte2, Wtn1, Wtn2, flag);
        ln_kernel<<<N_, 256, 0, stream>>>(h, ln_gamma, ln_beta, l*H_, hn, cat, flag);
        gemm_bt<0><<<dim3(N_/128, 8), 256, 0, stream>>>(hn, WtAB, nullptr, 0,
                                                        hnAB, nullptr, 512, 1024, flag);
        gemm_bt<0><<<dim3(E_/128, 4), 256, 0, stream>>>(femb, Wtf, nullptr, 0,
                                                        fembW, nullptr, 768, 512, flag);
        e1_assemble<<<E_, 256, 0, stream>>>(fembW, hnAB, ud, latp, cbias + l*B_*H_,
                                            We1, l, edge_index, e2g, e1, flag);
        gemm_bt<1><<<dim3(E_/128, 4), 256, 0, stream>>>(e1, Wte2, be2, l*H_,
                                                        e2, nullptr, 512, 512, flag);
        seg_mean<<<N_, 256, 0, stream>>>(e2, cat);
        gemm_bt<1><<<dim3(N_/128, 4), 256, 0, stream>>>(cat, Wtn1, bn1, l*H_,
                                                        n1s, nullptr, 1024, 512, flag);
        gemm_bt<2><<<dim3(N_/128, 4), 256, 0, stream>>>(n1s, Wtn2, bn2, l*H_,
                                                        nullptr, h, 512, 512, flag);
    }

    // ---- heads
    ln_kernel<<<N_, 256, 0, stream>>>(h, fln_gamma, fln_beta, 0, hln, nullptr, flag);
    pos_out<<<(N_*3 + 255)/256, 256, 0, stream>>>(hln, W_coord, d_out, flag);
    cell_out<<<B_, 512, 0, stream>>>(hln, W_latout, b_latout, num_atoms, d_out, flag);
}

// Round 4
// 1452.725 us; speedup vs baseline: 1.1705x; 1.1705x over previous
//
#include <hip/hip_runtime.h>
#include <hip/hip_bf16.h>

typedef __hip_bfloat16 bf16;
typedef __attribute__((ext_vector_type(8))) __bf16 bf16x8;
typedef __attribute__((ext_vector_type(4))) float f32x4;

#define B_   64
#define NPG_ 20
#define H_   512
#define TD_  256
#define NF_  128
#define NL_  6
#define A_   100
#define N_   (B_ * NPG_)            // 1280
#define E_   (B_ * NPG_ * (NPG_-1)) // 24320
#define EIN_ 2313

__device__ __forceinline__ float bf2f(bf16 x) { return __bfloat162float(x); }
__device__ __forceinline__ bf16  f2bf(float x) { return __float2bfloat16(x); }
__device__ __forceinline__ float siluf(float x) { return x / (1.0f + expf(-x)); }
// dual-dtype load: isb=1 -> bf16, else float32
__device__ __forceinline__ float ldf(const void* p, size_t i, int isb) {
    return isb ? bf2f(((const bf16*)p)[i]) : ((const float*)p)[i];
}

// ---------------------------------------------------------------- dtype detect on t (uniform [0,1))
__global__ void detect_dtype(const unsigned int* __restrict__ tw, int* __restrict__ flag) {
    if (threadIdx.x != 0) return;
    int cnt = 0;
    for (int i = 0; i < 32; i++) {
        unsigned b1 = (tw[i] >> 8) & 0xFF;
        if (b1 >= 0x20 && b1 < 0x40) cnt++;
    }
    *flag = (cnt >= 16) ? 1 : 0;
}

__global__ void ws_sentinel(bf16* out) { if (threadIdx.x == 0) out[0] = f2bf(1000.0f); }

// ---------------------------------------------------------------- prep: lattice -> ltl (B,3,3)
__global__ void prep_graph(const void* __restrict__ latp, float* __restrict__ ltl,
                           const int* __restrict__ flag) {
    int b = threadIdx.x;
    if (b >= B_) return;
    int isb = *flag;
    const float LM[3] = {1.575442910194397f, 1.7017393112182617f, 1.9781638383865356f};
    const float LS[3] = {0.24437622725963593f, 0.26526379585266113f, 0.3535512685775757f};
    float lp[6];
    for (int i = 0; i < 6; i++) lp[i] = ldf(latp, b*6 + i, isb);
    float len[3], c[3], s[3];
    for (int i = 0; i < 3; i++) len[i] = expf(lp[i] * LS[i] + LM[i]);
    for (int i = 0; i < 3; i++) {
        float sig = 1.0f / (1.0f + expf(-lp[3+i]));
        float deg = 59.9f + 60.2f * sig;
        float a = deg * 0.017453292519943295f;
        c[i] = cosf(a); s[i] = sinf(a);
    }
    float val = (c[0]*c[1] - c[2]) / (s[0]*s[1]);
    val = fminf(1.0f, fmaxf(-1.0f, val));
    float gs = acosf(val);
    float L[3][3];
    L[0][0] = len[0]*s[1]; L[0][1] = 0.0f;               L[0][2] = len[0]*c[1];
    L[1][0] = -len[1]*s[0]*cosf(gs); L[1][1] = len[1]*s[0]*sinf(gs); L[1][2] = len[1]*c[0];
    L[2][0] = 0.0f; L[2][1] = 0.0f; L[2][2] = len[2];
    for (int i = 0; i < 3; i++)
        for (int k = 0; k < 3; k++)
            ltl[b*9 + i*3 + k] = L[i][0]*L[k][0] + L[i][1]*L[k][1] + L[i][2]*L[k][2];
}

// ---------------------------------------------------------------- prep: q[j] = sum_d W_time[d]*W_latent[512+d][j]
__global__ __launch_bounds__(512) void prep_q(const void* __restrict__ W_time,
                                              const void* __restrict__ W_latent,
                                              float* __restrict__ q,
                                              const int* __restrict__ flag) {
    int j = threadIdx.x;
    int isb = *flag;
    float s0 = 0.0f, s1 = 0.0f, s2 = 0.0f, s3 = 0.0f;
    for (int d = 0; d < TD_; d += 4) {
        s0 += ldf(W_time, d+0, isb) * ldf(W_latent, (size_t)(H_ + d+0)*H_ + j, isb);
        s1 += ldf(W_time, d+1, isb) * ldf(W_latent, (size_t)(H_ + d+1)*H_ + j, isb);
        s2 += ldf(W_time, d+2, isb) * ldf(W_latent, (size_t)(H_ + d+2)*H_ + j, isb);
        s3 += ldf(W_time, d+3, isb) * ldf(W_latent, (size_t)(H_ + d+3)*H_ + j, isb);
    }
    q[j] = (s0 + s1) + (s2 + s3);
}

// ---------------------------------------------------------------- gather A rows for PQ gemm (7 slots of 128x512)
// slot 0: W_node (100 rows), slot 1+l: W_numatom[l] (100 rows); pad to 128 with 0
__global__ __launch_bounds__(256) void pq_gather(const void* __restrict__ W_node,
                                                 const void* __restrict__ W_numatom,
                                                 bf16* __restrict__ PQa,
                                                 const int* __restrict__ flag) {
    int z = blockIdx.x;
    int isb = *flag;
    for (int idx = threadIdx.x; idx < 128*512; idx += 256) {
        int r = idx >> 9, c = idx & 511;
        float v = 0.0f;
        if (r < A_) {
            if (z == 0) v = ldf(W_node, (size_t)r*512 + c, isb);
            else        v = ldf(W_numatom, ((size_t)(z-1)*A_ + r)*512 + c, isb);
        }
        PQa[(size_t)z*65536 + idx] = f2bf(v);
    }
}

// ---------------------------------------------------------------- transpose for PQ Bt (7 slots of 512x512)
// slot 0: W_latent[:512]^T ; slot 1+l: We1[l] rows 1801..2312 ^T
__global__ __launch_bounds__(256) void transpose_pq(const void* __restrict__ W_latent,
                                                    const void* __restrict__ We1,
                                                    bf16* __restrict__ PQbt,
                                                    const int* __restrict__ flag) {
    __shared__ bf16 tile[32][33];
    int z = blockIdx.z;
    int isb = *flag;
    const void* src = (z == 0) ? W_latent : We1;
    size_t off = (z == 0) ? 0 : ((size_t)(z-1)*EIN_ + 1801)*512;
    bf16* dst = PQbt + (size_t)z*512*512;
    int r0 = blockIdx.y * 32, c0 = blockIdx.x * 32;
    #pragma unroll
    for (int i = 0; i < 32; i += 8)
        tile[threadIdx.y + i][threadIdx.x] =
            f2bf(ldf(src, off + (size_t)(r0 + threadIdx.y + i)*512 + c0 + threadIdx.x, isb));
    __syncthreads();
    #pragma unroll
    for (int i = 0; i < 32; i += 8)
        dst[(size_t)(c0 + threadIdx.y + i)*512 + r0 + threadIdx.x] = tile[threadIdx.x][threadIdx.y + i];
}

// ---------------------------------------------------------------- per-layer weight transpose (Bt = N x K)
__global__ __launch_bounds__(256) void transpose_layer(
    const void* __restrict__ We1p, const void* __restrict__ We2p,
    const void* __restrict__ Wn1p, const void* __restrict__ Wn2p, size_t l,
    bf16* __restrict__ WtAB, bf16* __restrict__ Wtf, bf16* __restrict__ Wte2,
    bf16* __restrict__ Wtn1, bf16* __restrict__ Wtn2,
    const int* __restrict__ flag) {
    __shared__ bf16 tile[32][33];
    int which = blockIdx.z;
    int isb = *flag;
    const void* src; size_t off; bf16* dst; int R;
    switch (which) {
        case 0:  src = We1p; off = (l*EIN_ + 3)*512;    dst = WtAB;            R = 512;  break;
        case 1:  src = We1p; off = (l*EIN_ + 515)*512;  dst = WtAB + 512*512;  R = 512;  break;
        case 2:  src = We1p; off = (l*EIN_ + 1033)*512; dst = Wtf;             R = 768;  break;
        case 3:  src = We2p; off = l*512*512;           dst = Wte2;            R = 512;  break;
        case 4:  src = Wn1p; off = l*1024*512;          dst = Wtn1;            R = 1024; break;
        default: src = Wn2p; off = l*512*512;           dst = Wtn2;            R = 512;  break;
    }
    int r0 = blockIdx.y * 32, c0 = blockIdx.x * 32;
    if (r0 >= R) return;
    #pragma unroll
    for (int i = 0; i < 32; i += 8)
        tile[threadIdx.y + i][threadIdx.x] =
            f2bf(ldf(src, off + (size_t)(r0 + threadIdx.y + i)*512 + c0 + threadIdx.x, isb));
    __syncthreads();
    #pragma unroll
    for (int i = 0; i < 32; i += 8)
        dst[(size_t)(c0 + threadIdx.y + i)*R + r0 + threadIdx.x] = tile[threadIdx.x][threadIdx.y + i];
}

// ---------------------------------------------------------------- node embed: h[i][j] = P[at_i][j] + t[g]*q[j]
__global__ __launch_bounds__(512) void node_embed_fast(const bf16* __restrict__ P,
                                                       const float* __restrict__ q,
                                                       const void* __restrict__ t,
                                                       const int* __restrict__ atom_types,
                                                       const int* __restrict__ node2graph,
                                                       float* __restrict__ h,
                                                       const int* __restrict__ flag) {
    int i = blockIdx.x, j = threadIdx.x;
    int isb = *flag;
    int at = atom_types[i] - 1; if (at < 0) at = 0;   // ref clips low; high is out of one-hot range
    float pv = (at < A_) ? bf2f(P[(size_t)at*512 + j]) : 0.0f;
    float tv = ldf(t, node2graph[i], isb);
    h[(size_t)i*H_ + j] = pv + tv * q[j];
}

// ---------------------------------------------------------------- edge prep: frac_diff -> femb(bf16) + unit_dots(f32)
__global__ __launch_bounds__(384) void edge_prep(const void* __restrict__ frac,
                                                 const int* __restrict__ edge_index,
                                                 const int* __restrict__ e2g,
                                                 const float* __restrict__ ltl,
                                                 float* __restrict__ ud,
                                                 bf16* __restrict__ femb,
                                                 const int* __restrict__ flag) {
    const float TWO_PI_F = 6.283185307179586f;
    int e = blockIdx.x;
    int isb = *flag;
    int src = edge_index[e], dst = edge_index[E_ + e];
    int tid = threadIdx.x;
    int d = tid >> 7, k = tid & 127;
    float x = ldf(frac, src*3 + d, isb), y = ldf(frac, dst*3 + d, isb);
    float diff = y - x;
    float fd = diff - rintf(diff);   // == atan2(sin 2pi d, cos 2pi d)/2pi for d in (-1,1)
    float sv, cv;
    sincosf(fd * (TWO_PI_F * (float)k), &sv, &cv);
    femb[(size_t)e*768 + d*NF_ + k]       = f2bf(sv);
    femb[(size_t)e*768 + 384 + d*NF_ + k] = f2bf(cv);
    if (tid < 3) {
        int g = e2g[e];
        float f3[3];
        for (int dd = 0; dd < 3; dd++) {
            float df = ldf(frac, dst*3 + dd, isb) - ldf(frac, src*3 + dd, isb);
            f3[dd] = df - rintf(df);
        }
        float dots[3];
        for (int i = 0; i < 3; i++)
            dots[i] = ltl[g*9 + i*3 + 0]*f3[0] + ltl[g*9 + i*3 + 1]*f3[1] + ltl[g*9 + i*3 + 2]*f3[2];
        float nrm = sqrtf(dots[0]*dots[0] + dots[1]*dots[1] + dots[2]*dots[2]);
        ud[e*3 + tid] = dots[tid] / (nrm + 1e-12f);
    }
}

// ---------------------------------------------------------------- layernorm over H=512 -> cat[:, :512] (stride 1024)
__device__ __forceinline__ float block_sum_256(float v, float* red) {
    for (int o = 32; o; o >>= 1) v += __shfl_down(v, o);
    int w = threadIdx.x >> 6, lane = threadIdx.x & 63;
    if (lane == 0) red[w] = v;
    __syncthreads();
    float s = red[0] + red[1] + red[2] + red[3];
    __syncthreads();
    return s;
}

__global__ __launch_bounds__(256) void ln_kernel(const float* __restrict__ x,
                                                 const void* __restrict__ gamma,
                                                 const void* __restrict__ beta, size_t goff,
                                                 bf16* __restrict__ cat,
                                                 const int* __restrict__ flag) {
    __shared__ float red[4];
    size_t n = blockIdx.x;
    int tid = threadIdx.x;
    int isb = *flag;
    const float* xr = x + n*H_;
    float v0 = xr[tid], v1 = xr[tid + 256];
    float mu = block_sum_256(v0 + v1, red) * (1.0f/512.0f);
    float d0 = v0 - mu, d1 = v1 - mu;
    float var = block_sum_256(d0*d0 + d1*d1, red) * (1.0f/512.0f);
    float rs = 1.0f / sqrtf(var + 1e-5f);
    cat[n*1024 + tid]       = f2bf(d0*rs*ldf(gamma, goff + tid, isb)       + ldf(beta, goff + tid, isb));
    cat[n*1024 + 256 + tid] = f2bf(d1*rs*ldf(gamma, goff + tid + 256, isb) + ldf(beta, goff + tid + 256, isb));
}

// ---------------------------------------------------------------- bf16 MFMA GEMM: C(MxN) = A(MxK, lda) @ Bt(NxK)^T
// TM in {64,128}: tile TM x 128. 4 waves 2x2, wave tile (TM/2) x 64, frags 16x16x32.
// EPI: 0 = (+bias) bf16 store, 1 = silu bf16, 2 = Cf += silu (residual), 3 = fused e1-assemble
template<int EPI, int TM>
__global__ __launch_bounds__(256) void gemm_bt(
        const bf16* __restrict__ A, int lda,
        const bf16* __restrict__ Bt,
        const void* __restrict__ bias, size_t boff,
        bf16* __restrict__ Cb, float* __restrict__ Cf,
        int K, int N,
        size_t zsA, size_t zsB, size_t zsC,
        const int* __restrict__ flag,
        const bf16* __restrict__ hnAB, const bf16* __restrict__ Qc,
        const float* __restrict__ ud, const void* __restrict__ latp,
        const void* __restrict__ We1, size_t lidx,
        const int* __restrict__ edge_index, const int* __restrict__ e2g,
        const int* __restrict__ num_atoms) {
    constexpr int MT = TM / 32;                 // m-frags per wave
    __shared__ __align__(16) bf16 As[TM*32];
    __shared__ __align__(16) bf16 Bs[128*32];
    const int z = blockIdx.z;
    A  += (size_t)z * zsA;
    Bt += (size_t)z * zsB;
    const size_t coff = (size_t)z * zsC;
    const int tid = threadIdx.x;
    const int wave = tid >> 6, lane = tid & 63;
    const int lrow = lane & 15, lq = lane >> 4;
    const size_t m0 = (size_t)blockIdx.x * TM;
    const int n0 = blockIdx.y * 128;
    const int wm = (wave >> 1) * (TM/2), wn = (wave & 1) * 64;
    const int srow = tid >> 2;
    const int scol = (tid & 3) * 8;
    f32x4 acc[MT][4] = {};

    for (int k0 = 0; k0 < K; k0 += 32) {
        uint4 a0 = *(const uint4*)(A  + (m0 + srow) * lda + k0 + scol);
        uint4 a1;
        if (TM == 128) a1 = *(const uint4*)(A + (m0 + 64 + srow) * lda + k0 + scol);
        uint4 b0 = *(const uint4*)(Bt + (size_t)(n0 + srow) * K + k0 + scol);
        uint4 b1 = *(const uint4*)(Bt + (size_t)(n0 + 64 + srow) * K + k0 + scol);
        if (k0) __syncthreads();
        *(uint4*)(As + srow*32 + scol) = a0;
        if (TM == 128) *(uint4*)(As + (64 + srow)*32 + scol) = a1;
        *(uint4*)(Bs + srow*32 + scol)        = b0;
        *(uint4*)(Bs + (64 + srow)*32 + scol) = b1;
        __syncthreads();
        bf16x8 af[MT], bfr[4];
        #pragma unroll
        for (int mt = 0; mt < MT; mt++)
            af[mt] = *(const bf16x8*)(As + (wm + mt*16 + lrow)*32 + lq*8);
        #pragma unroll
        for (int nt = 0; nt < 4; nt++)
            bfr[nt] = *(const bf16x8*)(Bs + (wn + nt*16 + lrow)*32 + lq*8);
        #pragma unroll
        for (int mt = 0; mt < MT; mt++)
            #pragma unroll
            for (int nt = 0; nt < 4; nt++)
                acc[mt][nt] = __builtin_amdgcn_mfma_f32_16x16x32_bf16(af[mt], bfr[nt], acc[mt][nt], 0, 0, 0);
    }

    if constexpr (EPI == 3) {
        // fused e1-assemble: row = edge e, col = j
        const int isb = *flag;
        // hoist per-col terms: 9 geometry weight rows of We1 + be1
        float w9[4][9], b1v[4];
        #pragma unroll
        for (int nt = 0; nt < 4; nt++) {
            int col = n0 + wn + nt*16 + lrow;
            size_t wb = lidx*EIN_*512 + col;
            w9[nt][0] = ldf(We1, wb + 0*512, isb);
            w9[nt][1] = ldf(We1, wb + 1*512, isb);
            w9[nt][2] = ldf(We1, wb + 2*512, isb);
            #pragma unroll
            for (int i = 0; i < 6; i++) w9[nt][3+i] = ldf(We1, wb + (size_t)(1027+i)*512, isb);
            b1v[nt] = ldf(bias, boff + col, isb);
        }
        #pragma unroll
        for (int mt = 0; mt < MT; mt++) {
            #pragma unroll
            for (int r = 0; r < 4; r++) {
                size_t e = m0 + wm + mt*16 + lq*4 + r;
                int se = edge_index[e], de = edge_index[E_ + e], g = e2g[e];
                int na = num_atoms[g] - 1;
                bool okna = (na >= 0 && na < A_); if (!okna) na = 0;
                float u0 = ud[e*3], u1 = ud[e*3+1], u2 = ud[e*3+2];
                float la[6];
                #pragma unroll
                for (int i = 0; i < 6; i++) la[i] = ldf(latp, g*6 + i, isb);
                #pragma unroll
                for (int nt = 0; nt < 4; nt++) {
                    int col = n0 + wn + nt*16 + lrow;
                    float x = acc[mt][nt][r] + b1v[nt]
                            + bf2f(hnAB[(size_t)se*1024 + col])
                            + bf2f(hnAB[(size_t)de*1024 + 512 + col])
                            + (okna ? bf2f(Qc[(size_t)(1+lidx)*65536 + (size_t)na*512 + col]) : 0.0f)
                            + u0*w9[nt][0] + u1*w9[nt][1] + u2*w9[nt][2]
                            + la[0]*w9[nt][3] + la[1]*w9[nt][4] + la[2]*w9[nt][5]
                            + la[3]*w9[nt][6] + la[4]*w9[nt][7] + la[5]*w9[nt][8];
                    Cb[e*512 + col] = f2bf(siluf(x));
                }
            }
        }
    } else {
        const int isb = bias ? *flag : 0;
        #pragma unroll
        for (int mt = 0; mt < MT; mt++)
            #pragma unroll
            for (int nt = 0; nt < 4; nt++) {
                int col = n0 + wn + nt*16 + lrow;
                float bv = bias ? ldf(bias, boff + col, isb) : 0.0f;
                #pragma unroll
                for (int r = 0; r < 4; r++) {
                    size_t row = m0 + wm + mt*16 + lq*4 + r;
                    float x = acc[mt][nt][r] + bv;
                    if (EPI == 0)      Cb[coff + row*N + col] = f2bf(x);
                    else if (EPI == 1) Cb[coff + row*N + col] = f2bf(siluf(x));
                    else               Cf[coff + row*N + col] += siluf(x);
                }
            }
    }
}

// ---------------------------------------------------------------- agg: mean over each node's 19 contiguous edges
__global__ __launch_bounds__(256) void seg_mean(const bf16* __restrict__ e2,
                                                bf16* __restrict__ cat) {
    int n = blockIdx.x;
    #pragma unroll
    for (int jj = 0; jj < 2; jj++) {
        int j = threadIdx.x + jj*256;
        const bf16* base = e2 + (size_t)n*19*H_ + j;
        float s = 0.0f;
        #pragma unroll
        for (int i = 0; i < 19; i++) s += bf2f(base[(size_t)i*H_]);
        cat[(size_t)n*1024 + 512 + j] = f2bf(s / 19.0f);
    }
}

// ---------------------------------------------------------------- heads (hln lives in cat[:, :512], stride 1024)
__global__ __launch_bounds__(256) void pos_out(const bf16* __restrict__ hln,
                                               const void* __restrict__ W_coord,
                                               void* __restrict__ out,
                                               const int* __restrict__ flag) {
    int wave = threadIdx.x >> 6, lane = threadIdx.x & 63;
    int n = blockIdx.x*4 + wave;
    int isb = *flag;
    float s0 = 0, s1 = 0, s2 = 0;
    for (int k = lane; k < H_; k += 64) {
        float hv = bf2f(hln[(size_t)n*1024 + k]);
        s0 += hv * ldf(W_coord, k*3 + 0, isb);
        s1 += hv * ldf(W_coord, k*3 + 1, isb);
        s2 += hv * ldf(W_coord, k*3 + 2, isb);
    }
    for (int o = 32; o; o >>= 1) {
        s0 += __shfl_down(s0, o); s1 += __shfl_down(s1, o); s2 += __shfl_down(s2, o);
    }
    if (lane == 0) {
        if (isb) { bf16* o = (bf16*)out;  o[n*3] = f2bf(s0); o[n*3+1] = f2bf(s1); o[n*3+2] = f2bf(s2); }
        else     { float* o = (float*)out; o[n*3] = s0; o[n*3+1] = s1; o[n*3+2] = s2; }
    }
}

__global__ __launch_bounds__(512) void cell_out(const bf16* __restrict__ hln,
                                                const void* __restrict__ W_latout,
                                                const void* __restrict__ b_latout,
                                                const int* __restrict__ num_atoms,
                                                void* __restrict__ out,
                                                const int* __restrict__ flag) {
    __shared__ float red[8*6];
    int b = blockIdx.x, j = threadIdx.x;
    int isb = *flag;
    float s = 0.0f;
    for (int i = 0; i < NPG_; i++) s += bf2f(hln[(size_t)(b*NPG_ + i)*1024 + j]);
    float m = s / (float)num_atoms[b];
    float p[6];
    #pragma unroll
    for (int c = 0; c < 6; c++)
        p[c] = m * ldf(W_latout, j*6 + c, isb) + s * ldf(W_latout, (512 + j)*6 + c, isb);
    int w = j >> 6, lane = j & 63;
    #pragma unroll
    for (int c = 0; c < 6; c++) {
        float v = p[c];
        for (int o = 32; o; o >>= 1) v += __shfl_down(v, o);
        if (lane == 0) red[w*6 + c] = v;
    }
    __syncthreads();
    if (j < 6) {
        float v = 0.0f;
        for (int w2 = 0; w2 < 8; w2++) v += red[w2*6 + j];
        float r = v + ldf(b_latout, j, isb);
        if (isb) ((bf16*)out)[N_*3 + b*6 + j] = f2bf(r);
        else     ((float*)out)[N_*3 + b*6 + j] = r;
    }
}

// ================================================================ host
extern "C" void kernel_launch(void* const* d_in, const int* in_sizes, int n_in,
                              void* d_out, int out_size, void* d_ws, size_t ws_size,
                              hipStream_t stream) {
    const void* t          = d_in[0];
    const void* frac       = d_in[1];
    const void* latp       = d_in[2];
    const int*  atom_types = (const int*)d_in[3];
    const int*  num_atoms  = (const int*)d_in[4];
    const int*  node2graph = (const int*)d_in[5];
    const int*  edge_index = (const int*)d_in[6];
    const int*  e2g        = (const int*)d_in[7];
    const void* W_node     = d_in[8];
    const void* W_time     = d_in[9];
    const void* W_latent   = d_in[10];
    const void* ln_gamma   = d_in[11];
    const void* ln_beta    = d_in[12];
    const void* We1        = d_in[13];
    const void* be1        = d_in[14];
    const void* We2        = d_in[15];
    const void* be2        = d_in[16];
    const void* Wn1        = d_in[17];
    const void* bn1        = d_in[18];
    const void* Wn2        = d_in[19];
    const void* bn2        = d_in[20];
    const void* W_numatom  = d_in[21];
    const void* fln_gamma  = d_in[22];
    const void* fln_beta   = d_in[23];
    const void* W_coord    = d_in[24];
    const void* W_latout   = d_in[25];
    const void* b_latout   = d_in[26];

    // workspace carve (~101.5 MB; fits proven >=102.7 MB budget)
    char* p = (char*)d_ws;
    auto alloc = [&](size_t bytes) { char* r = p; p += (bytes + 255) & ~(size_t)255; return r; };
    int*   flag  = (int*)alloc(4);
    float* ltl   = (float*)alloc((size_t)B_*9*4);
    float* q     = (float*)alloc((size_t)H_*4);
    float* h     = (float*)alloc((size_t)N_*H_*4);
    float* ud    = (float*)alloc((size_t)E_*3*4);
    bf16* hnAB  = (bf16*)alloc((size_t)N_*1024*2);
    bf16* femb  = (bf16*)alloc((size_t)E_*768*2);
    bf16* e1    = (bf16*)alloc((size_t)E_*H_*2);    // prep-phase alias: PQa (7*128*512)
    bf16* e2    = (bf16*)alloc((size_t)E_*H_*2);    // prep-phase alias: PQbt (7*512*512)
    bf16* cat   = (bf16*)alloc((size_t)N_*1024*2);
    bf16* n1s   = (bf16*)alloc((size_t)N_*H_*2);
    bf16* PQc   = (bf16*)alloc((size_t)7*128*512*2);
    bf16* WtAB  = (bf16*)alloc((size_t)1024*512*2);
    bf16* Wtf   = (bf16*)alloc((size_t)512*768*2);
    bf16* Wte2  = (bf16*)alloc((size_t)512*512*2);
    bf16* Wtn1  = (bf16*)alloc((size_t)512*1024*2);
    bf16* Wtn2  = (bf16*)alloc((size_t)512*512*2);
    bf16* PQa   = e1;   // dead before layer loop
    bf16* PQbt  = e2;   // dead before layer loop

    if ((size_t)(p - (char*)d_ws) > ws_size) {
        ws_sentinel<<<1, 64, 0, stream>>>((bf16*)d_out);
        return;
    }

    // ---- prep
    detect_dtype<<<1, 64, 0, stream>>>((const unsigned int*)t, flag);
    prep_graph<<<1, 64, 0, stream>>>(latp, ltl, flag);
    prep_q<<<1, 512, 0, stream>>>(W_time, W_latent, q, flag);
    pq_gather<<<7, 256, 0, stream>>>(W_node, W_numatom, PQa, flag);
    transpose_pq<<<dim3(16, 16, 7), dim3(32, 8), 0, stream>>>(W_latent, We1, PQbt, flag);
    // PQc[z] = PQa[z] @ PQbt[z]^T  (z=0: P, z=1+l: Q[l])
    gemm_bt<0,128><<<dim3(1, 4, 7), 256, 0, stream>>>(
        PQa, 512, PQbt, nullptr, 0, PQc, nullptr, 512, 512,
        (size_t)128*512, (size_t)512*512, (size_t)128*512,
        flag, nullptr, nullptr, nullptr, nullptr, nullptr, 0, nullptr, nullptr, nullptr);
    node_embed_fast<<<N_, 512, 0, stream>>>(PQc, q, t, atom_types, node2graph, h, flag);
    edge_prep<<<E_, 384, 0, stream>>>(frac, edge_index, e2g, ltl, ud, femb, flag);

    // ---- layers
    for (size_t l = 0; l < NL_; l++) {
        transpose_layer<<<dim3(16, 32, 6), dim3(32, 8), 0, stream>>>(
            We1, We2, Wn1, Wn2, l, WtAB, Wtf, Wte2, Wtn1, Wtn2, flag);
        ln_kernel<<<N_, 256, 0, stream>>>(h, ln_gamma, ln_beta, l*H_, cat, flag);
        // hnAB = hn @ [WA|WB]   (A = cat[:, :512], lda=1024)
        gemm_bt<0,64><<<dim3(N_/64, 8), 256, 0, stream>>>(
            cat, 1024, WtAB, nullptr, 0, hnAB, nullptr, 512, 1024, 0, 0, 0,
            flag, nullptr, nullptr, nullptr, nullptr, nullptr, 0, nullptr, nullptr, nullptr);
        // e1 = silu(femb@Wf + hnA[src] + hnB[dst] + geo + Q[na] + be1)   [fused epilogue]
        gemm_bt<3,128><<<dim3(E_/128, 4), 256, 0, stream>>>(
            femb, 768, Wtf, be1, l*H_, e1, nullptr, 768, 512, 0, 0, 0,
            flag, hnAB, PQc, ud, latp, We1, l, edge_index, e2g, num_atoms);
        // e2 = silu(e1@We2 + be2)
        gemm_bt<1,128><<<dim3(E_/128, 4), 256, 0, stream>>>(
            e1, 512, Wte2, be2, l*H_, e2, nullptr, 512, 512, 0, 0, 0,
            flag, nullptr, nullptr, nullptr, nullptr, nullptr, 0, nullptr, nullptr, nullptr);
        seg_mean<<<N_, 256, 0, stream>>>(e2, cat);
        // n1s = silu(cat@Wn1 + bn1)
        gemm_bt<1,64><<<dim3(N_/64, 4), 256, 0, stream>>>(
            cat, 1024, Wtn1, bn1, l*H_, n1s, nullptr, 1024, 512, 0, 0, 0,
            flag, nullptr, nullptr, nullptr, nullptr, nullptr, 0, nullptr, nullptr, nullptr);
        // h += silu(n1s@Wn2 + bn2)
        gemm_bt<2,64><<<dim3(N_/64, 4), 256, 0, stream>>>(
            n1s, 512, Wtn2, bn2, l*H_, nullptr, h, 512, 512, 0, 0, 0,
            flag, nullptr, nullptr, nullptr, nullptr, nullptr, 0, nullptr, nullptr, nullptr);
    }

    // ---- heads (final LN into cat[:, :512])
    ln_kernel<<<N_, 256, 0, stream>>>(h, fln_gamma, fln_beta, 0, cat, flag);
    pos_out<<<N_/4, 256, 0, stream>>>(cat, W_coord, d_out, flag);
    cell_out<<<B_, 512, 0, stream>>>(cat, W_latout, b_latout, num_atoms, d_out, flag);
}

// Round 5
// 1322.039 us; speedup vs baseline: 1.2862x; 1.0989x over previous
//
#include <hip/hip_runtime.h>
#include <hip/hip_bf16.h>

typedef __hip_bfloat16 bf16;
typedef __attribute__((ext_vector_type(8))) __bf16 bf16x8;
typedef __attribute__((ext_vector_type(4))) float f32x4;

#define B_   64
#define NPG_ 20
#define H_   512
#define TD_  256
#define NF_  128
#define NL_  6
#define A_   100
#define N_   (B_ * NPG_)            // 1280
#define E_   (B_ * NPG_ * (NPG_-1)) // 24320
#define EIN_ 2313

__device__ __forceinline__ float bf2f(bf16 x) { return __bfloat162float(x); }
__device__ __forceinline__ bf16  f2bf(float x) { return __float2bfloat16(x); }
__device__ __forceinline__ float siluf(float x) { return x / (1.0f + expf(-x)); }
// dual-dtype load: isb=1 -> bf16, else float32
__device__ __forceinline__ float ldf(const void* p, size_t i, int isb) {
    return isb ? bf2f(((const bf16*)p)[i]) : ((const float*)p)[i];
}
// async global->LDS, 16B per lane; lds dst is wave-uniform base + lane*16 (m97/m104)
__device__ __forceinline__ void async_cp16(const bf16* src, bf16* dst) {
    __builtin_amdgcn_global_load_lds(
        (const __attribute__((address_space(1))) unsigned int*)src,
        (__attribute__((address_space(3))) unsigned int*)dst,
        16, 0, 0);
}

// ---------------------------------------------------------------- dtype detect on t (uniform [0,1))
__global__ void detect_dtype(const unsigned int* __restrict__ tw, int* __restrict__ flag) {
    if (threadIdx.x != 0) return;
    int cnt = 0;
    for (int i = 0; i < 32; i++) {
        unsigned b1 = (tw[i] >> 8) & 0xFF;
        if (b1 >= 0x20 && b1 < 0x40) cnt++;
    }
    *flag = (cnt >= 16) ? 1 : 0;
}

__global__ void ws_sentinel(bf16* out) { if (threadIdx.x == 0) out[0] = f2bf(1000.0f); }

// ---------------------------------------------------------------- prep: lattice -> ltl (B,3,3)
__global__ void prep_graph(const void* __restrict__ latp, float* __restrict__ ltl,
                           const int* __restrict__ flag) {
    int b = threadIdx.x;
    if (b >= B_) return;
    int isb = *flag;
    const float LM[3] = {1.575442910194397f, 1.7017393112182617f, 1.9781638383865356f};
    const float LS[3] = {0.24437622725963593f, 0.26526379585266113f, 0.3535512685775757f};
    float lp[6];
    for (int i = 0; i < 6; i++) lp[i] = ldf(latp, b*6 + i, isb);
    float len[3], c[3], s[3];
    for (int i = 0; i < 3; i++) len[i] = expf(lp[i] * LS[i] + LM[i]);
    for (int i = 0; i < 3; i++) {
        float sig = 1.0f / (1.0f + expf(-lp[3+i]));
        float deg = 59.9f + 60.2f * sig;
        float a = deg * 0.017453292519943295f;
        c[i] = cosf(a); s[i] = sinf(a);
    }
    float val = (c[0]*c[1] - c[2]) / (s[0]*s[1]);
    val = fminf(1.0f, fmaxf(-1.0f, val));
    float gs = acosf(val);
    float L[3][3];
    L[0][0] = len[0]*s[1]; L[0][1] = 0.0f;               L[0][2] = len[0]*c[1];
    L[1][0] = -len[1]*s[0]*cosf(gs); L[1][1] = len[1]*s[0]*sinf(gs); L[1][2] = len[1]*c[0];
    L[2][0] = 0.0f; L[2][1] = 0.0f; L[2][2] = len[2];
    for (int i = 0; i < 3; i++)
        for (int k = 0; k < 3; k++)
            ltl[b*9 + i*3 + k] = L[i][0]*L[k][0] + L[i][1]*L[k][1] + L[i][2]*L[k][2];
}

// ---------------------------------------------------------------- prep: q[j] = sum_d W_time[d]*W_latent[512+d][j]
__global__ __launch_bounds__(512) void prep_q(const void* __restrict__ W_time,
                                              const void* __restrict__ W_latent,
                                              float* __restrict__ q,
                                              const int* __restrict__ flag) {
    int j = threadIdx.x;
    int isb = *flag;
    float s0 = 0.0f, s1 = 0.0f, s2 = 0.0f, s3 = 0.0f;
    for (int d = 0; d < TD_; d += 4) {
        s0 += ldf(W_time, d+0, isb) * ldf(W_latent, (size_t)(H_ + d+0)*H_ + j, isb);
        s1 += ldf(W_time, d+1, isb) * ldf(W_latent, (size_t)(H_ + d+1)*H_ + j, isb);
        s2 += ldf(W_time, d+2, isb) * ldf(W_latent, (size_t)(H_ + d+2)*H_ + j, isb);
        s3 += ldf(W_time, d+3, isb) * ldf(W_latent, (size_t)(H_ + d+3)*H_ + j, isb);
    }
    q[j] = (s0 + s1) + (s2 + s3);
}

// ---------------------------------------------------------------- gather A rows for PQ gemm (7 slots of 128x512)
// grid (7, 16): z = slot, y = 4096-elem chunk
__global__ __launch_bounds__(256) void pq_gather(const void* __restrict__ W_node,
                                                 const void* __restrict__ W_numatom,
                                                 bf16* __restrict__ PQa,
                                                 const int* __restrict__ flag) {
    int z = blockIdx.x, ch = blockIdx.y;
    int isb = *flag;
    int base = ch * 4096;
    for (int idx = base + threadIdx.x; idx < base + 4096; idx += 256) {
        int r = idx >> 9, c = idx & 511;
        float v = 0.0f;
        if (r < A_) {
            if (z == 0) v = ldf(W_node, (size_t)r*512 + c, isb);
            else        v = ldf(W_numatom, ((size_t)(z-1)*A_ + r)*512 + c, isb);
        }
        PQa[(size_t)z*65536 + idx] = f2bf(v);
    }
}

// ---------------------------------------------------------------- transpose for PQ Bt (7 slots of 512x512)
__global__ __launch_bounds__(256) void transpose_pq(const void* __restrict__ W_latent,
                                                    const void* __restrict__ We1,
                                                    bf16* __restrict__ PQbt,
                                                    const int* __restrict__ flag) {
    __shared__ bf16 tile[32][33];
    int z = blockIdx.z;
    int isb = *flag;
    const void* src = (z == 0) ? W_latent : We1;
    size_t off = (z == 0) ? 0 : ((size_t)(z-1)*EIN_ + 1801)*512;
    bf16* dst = PQbt + (size_t)z*512*512;
    int r0 = blockIdx.y * 32, c0 = blockIdx.x * 32;
    #pragma unroll
    for (int i = 0; i < 32; i += 8)
        tile[threadIdx.y + i][threadIdx.x] =
            f2bf(ldf(src, off + (size_t)(r0 + threadIdx.y + i)*512 + c0 + threadIdx.x, isb));
    __syncthreads();
    #pragma unroll
    for (int i = 0; i < 32; i += 8)
        dst[(size_t)(c0 + threadIdx.y + i)*512 + r0 + threadIdx.x] = tile[threadIdx.x][threadIdx.y + i];
}

// ---------------------------------------------------------------- per-layer weight transpose (Bt = N x K)
__global__ __launch_bounds__(256) void transpose_layer(
    const void* __restrict__ We1p, const void* __restrict__ We2p,
    const void* __restrict__ Wn1p, const void* __restrict__ Wn2p, size_t l,
    bf16* __restrict__ WtAB, bf16* __restrict__ Wtf, bf16* __restrict__ Wte2,
    bf16* __restrict__ Wtn1, bf16* __restrict__ Wtn2,
    const int* __restrict__ flag) {
    __shared__ bf16 tile[32][33];
    int which = blockIdx.z;
    int isb = *flag;
    const void* src; size_t off; bf16* dst; int R;
    switch (which) {
        case 0:  src = We1p; off = (l*EIN_ + 3)*512;    dst = WtAB;            R = 512;  break;
        case 1:  src = We1p; off = (l*EIN_ + 515)*512;  dst = WtAB + 512*512;  R = 512;  break;
        case 2:  src = We1p; off = (l*EIN_ + 1033)*512; dst = Wtf;             R = 768;  break;
        case 3:  src = We2p; off = l*512*512;           dst = Wte2;            R = 512;  break;
        case 4:  src = Wn1p; off = l*1024*512;          dst = Wtn1;            R = 1024; break;
        default: src = Wn2p; off = l*512*512;           dst = Wtn2;            R = 512;  break;
    }
    int r0 = blockIdx.y * 32, c0 = blockIdx.x * 32;
    if (r0 >= R) return;
    #pragma unroll
    for (int i = 0; i < 32; i += 8)
        tile[threadIdx.y + i][threadIdx.x] =
            f2bf(ldf(src, off + (size_t)(r0 + threadIdx.y + i)*512 + c0 + threadIdx.x, isb));
    __syncthreads();
    #pragma unroll
    for (int i = 0; i < 32; i += 8)
        dst[(size_t)(c0 + threadIdx.y + i)*R + r0 + threadIdx.x] = tile[threadIdx.x][threadIdx.y + i];
}

// ---------------------------------------------------------------- node embed: h[i][j] = P[at_i][j] + t[g]*q[j]
__global__ __launch_bounds__(512) void node_embed_fast(const bf16* __restrict__ P,
                                                       const float* __restrict__ q,
                                                       const void* __restrict__ t,
                                                       const int* __restrict__ atom_types,
                                                       const int* __restrict__ node2graph,
                                                       float* __restrict__ h,
                                                       const int* __restrict__ flag) {
    int i = blockIdx.x, j = threadIdx.x;
    int isb = *flag;
    int at = atom_types[i] - 1; if (at < 0) at = 0;
    float pv = (at < A_) ? bf2f(P[(size_t)at*512 + j]) : 0.0f;
    float tv = ldf(t, node2graph[i], isb);
    h[(size_t)i*H_ + j] = pv + tv * q[j];
}

// ---------------------------------------------------------------- edge prep: frac_diff -> femb(bf16) + unit_dots(f32)
__global__ __launch_bounds__(384) void edge_prep(const void* __restrict__ frac,
                                                 const int* __restrict__ edge_index,
                                                 const int* __restrict__ e2g,
                                                 const float* __restrict__ ltl,
                                                 float* __restrict__ ud,
                                                 bf16* __restrict__ femb,
                                                 const int* __restrict__ flag) {
    const float TWO_PI_F = 6.283185307179586f;
    int e = blockIdx.x;
    int isb = *flag;
    int src = edge_index[e], dst = edge_index[E_ + e];
    int tid = threadIdx.x;
    int d = tid >> 7, k = tid & 127;
    float x = ldf(frac, src*3 + d, isb), y = ldf(frac, dst*3 + d, isb);
    float diff = y - x;
    float fd = diff - rintf(diff);
    float sv, cv;
    sincosf(fd * (TWO_PI_F * (float)k), &sv, &cv);
    femb[(size_t)e*768 + d*NF_ + k]       = f2bf(sv);
    femb[(size_t)e*768 + 384 + d*NF_ + k] = f2bf(cv);
    if (tid < 3) {
        int g = e2g[e];
        float f3[3];
        for (int dd = 0; dd < 3; dd++) {
            float df = ldf(frac, dst*3 + dd, isb) - ldf(frac, src*3 + dd, isb);
            f3[dd] = df - rintf(df);
        }
        float dots[3];
        for (int i = 0; i < 3; i++)
            dots[i] = ltl[g*9 + i*3 + 0]*f3[0] + ltl[g*9 + i*3 + 1]*f3[1] + ltl[g*9 + i*3 + 2]*f3[2];
        float nrm = sqrtf(dots[0]*dots[0] + dots[1]*dots[1] + dots[2]*dots[2]);
        ud[e*3 + tid] = dots[tid] / (nrm + 1e-12f);
    }
}

// ---------------------------------------------------------------- layernorm over H=512 -> cat[:, :512] (stride 1024)
__device__ __forceinline__ float block_sum_256(float v, float* red) {
    for (int o = 32; o; o >>= 1) v += __shfl_down(v, o);
    int w = threadIdx.x >> 6, lane = threadIdx.x & 63;
    if (lane == 0) red[w] = v;
    __syncthreads();
    float s = red[0] + red[1] + red[2] + red[3];
    __syncthreads();
    return s;
}

__global__ __launch_bounds__(256) void ln_kernel(const float* __restrict__ x,
                                                 const void* __restrict__ gamma,
                                                 const void* __restrict__ beta, size_t goff,
                                                 bf16* __restrict__ cat,
                                                 const int* __restrict__ flag) {
    __shared__ float red[4];
    size_t n = blockIdx.x;
    int tid = threadIdx.x;
    int isb = *flag;
    const float* xr = x + n*H_;
    float v0 = xr[tid], v1 = xr[tid + 256];
    float mu = block_sum_256(v0 + v1, red) * (1.0f/512.0f);
    float d0 = v0 - mu, d1 = v1 - mu;
    float var = block_sum_256(d0*d0 + d1*d1, red) * (1.0f/512.0f);
    float rs = 1.0f / sqrtf(var + 1e-5f);
    cat[n*1024 + tid]       = f2bf(d0*rs*ldf(gamma, goff + tid, isb)       + ldf(beta, goff + tid, isb));
    cat[n*1024 + 256 + tid] = f2bf(d1*rs*ldf(gamma, goff + tid + 256, isb) + ldf(beta, goff + tid + 256, isb));
}

// ---------------------------------------------------------------- bf16 MFMA GEMM: C(MxN) = A(MxK, lda) @ Bt(NxK)^T
// grid: x = col-blocks (fast, L2 reuse of A), y = row-blocks.
// Staging via global_load_lds (16B/lane) with k-chunk swizzle gk=(c+(r>>1))&3 to kill LDS bank conflicts.
// EPI: 0 = (+bias) bf16 store, 1 = silu bf16, 2 = Cf += silu (residual), 3 = fused e1-assemble
template<int EPI, int TM>
__global__ __launch_bounds__(256) void gemm_bt(
        const bf16* __restrict__ A, int lda,
        const bf16* __restrict__ Bt,
        const void* __restrict__ bias, size_t boff,
        bf16* __restrict__ Cb, float* __restrict__ Cf,
        int K, int N,
        size_t zsA, size_t zsB, size_t zsC,
        const int* __restrict__ flag,
        const bf16* __restrict__ hnAB, const bf16* __restrict__ Qc,
        const float* __restrict__ ud, const void* __restrict__ latp,
        const void* __restrict__ We1, size_t lidx,
        const int* __restrict__ edge_index, const int* __restrict__ e2g,
        const int* __restrict__ num_atoms) {
    constexpr int MT = TM / 32;
    __shared__ __align__(16) bf16 As[TM*32];
    __shared__ __align__(16) bf16 Bs[128*32];
    const int z = blockIdx.z;
    A  += (size_t)z * zsA;
    Bt += (size_t)z * zsB;
    const size_t coff = (size_t)z * zsC;
    const int tid = threadIdx.x;
    const int wave = tid >> 6, lane = tid & 63;
    const int lrow = lane & 15, lq = lane >> 4;
    const size_t m0 = (size_t)blockIdx.y * TM;
    const int n0 = blockIdx.x * 128;
    const int wm = (wave >> 1) * (TM/2), wn = (wave & 1) * 64;
    const int ar = lane >> 2;        // row within 16-row async window
    const int ac = lane & 3;         // 16B slot within row
    f32x4 acc[MT][4] = {};

    for (int k0 = 0; k0 < K; k0 += 32) {
        if (k0) __syncthreads();
        #pragma unroll
        for (int hh = 0; hh < TM/64; hh++) {
            int R = hh*64 + wave*16;
            int r = R + ar;
            int gk = (ac + ((r >> 1) & 3)) & 3;
            async_cp16(A + (m0 + r)*lda + k0 + gk*8, As + R*32);
        }
        #pragma unroll
        for (int hh = 0; hh < 2; hh++) {
            int R = hh*64 + wave*16;
            int r = R + ar;
            int gk = (ac + ((r >> 1) & 3)) & 3;
            async_cp16(Bt + (size_t)(n0 + r)*K + k0 + gk*8, Bs + R*32);
        }
        __syncthreads();
        bf16x8 af[MT], bfr[4];
        #pragma unroll
        for (int mt = 0; mt < MT; mt++) {
            int r = wm + mt*16 + lrow;
            int c = (lq - ((r >> 1) & 3)) & 3;
            af[mt] = *(const bf16x8*)(As + r*32 + c*8);
        }
        #pragma unroll
        for (int nt = 0; nt < 4; nt++) {
            int r = wn + nt*16 + lrow;
            int c = (lq - ((r >> 1) & 3)) & 3;
            bfr[nt] = *(const bf16x8*)(Bs + r*32 + c*8);
        }
        #pragma unroll
        for (int mt = 0; mt < MT; mt++)
            #pragma unroll
            for (int nt = 0; nt < 4; nt++)
                acc[mt][nt] = __builtin_amdgcn_mfma_f32_16x16x32_bf16(af[mt], bfr[nt], acc[mt][nt], 0, 0, 0);
    }

    if constexpr (EPI == 3) {
        const int isb = *flag;
        float w9[4][9], b1v[4];
        #pragma unroll
        for (int nt = 0; nt < 4; nt++) {
            int col = n0 + wn + nt*16 + lrow;
            size_t wb = lidx*EIN_*512 + col;
            w9[nt][0] = ldf(We1, wb + 0*512, isb);
            w9[nt][1] = ldf(We1, wb + 1*512, isb);
            w9[nt][2] = ldf(We1, wb + 2*512, isb);
            #pragma unroll
            for (int i = 0; i < 6; i++) w9[nt][3+i] = ldf(We1, wb + (size_t)(1027+i)*512, isb);
            b1v[nt] = ldf(bias, boff + col, isb);
        }
        #pragma unroll
        for (int mt = 0; mt < MT; mt++) {
            #pragma unroll
            for (int r = 0; r < 4; r++) {
                size_t e = m0 + wm + mt*16 + (lane>>4)*4 + r;
                int se = edge_index[e], de = edge_index[E_ + e], g = e2g[e];
                int na = num_atoms[g] - 1;
                bool okna = (na >= 0 && na < A_); if (!okna) na = 0;
                float u0 = ud[e*3], u1 = ud[e*3+1], u2 = ud[e*3+2];
                float la[6];
                #pragma unroll
                for (int i = 0; i < 6; i++) la[i] = ldf(latp, g*6 + i, isb);
                #pragma unroll
                for (int nt = 0; nt < 4; nt++) {
                    int col = n0 + wn + nt*16 + lrow;
                    float x = acc[mt][nt][r] + b1v[nt]
                            + bf2f(hnAB[(size_t)se*1024 + col])
                            + bf2f(hnAB[(size_t)de*1024 + 512 + col])
                            + (okna ? bf2f(Qc[(size_t)(1+lidx)*65536 + (size_t)na*512 + col]) : 0.0f)
                            + u0*w9[nt][0] + u1*w9[nt][1] + u2*w9[nt][2]
                            + la[0]*w9[nt][3] + la[1]*w9[nt][4] + la[2]*w9[nt][5]
                            + la[3]*w9[nt][6] + la[4]*w9[nt][7] + la[5]*w9[nt][8];
                    Cb[e*512 + col] = f2bf(siluf(x));
                }
            }
        }
    } else {
        const int isb = bias ? *flag : 0;
        #pragma unroll
        for (int mt = 0; mt < MT; mt++)
            #pragma unroll
            for (int nt = 0; nt < 4; nt++) {
                int col = n0 + wn + nt*16 + lrow;
                float bv = bias ? ldf(bias, boff + col, isb) : 0.0f;
                #pragma unroll
                for (int r = 0; r < 4; r++) {
                    size_t row = m0 + wm + mt*16 + lq*4 + r;
                    float x = acc[mt][nt][r] + bv;
                    if (EPI == 0)      Cb[coff + row*N + col] = f2bf(x);
                    else if (EPI == 1) Cb[coff + row*N + col] = f2bf(siluf(x));
                    else               Cf[coff + row*N + col] += siluf(x);
                }
            }
    }
}

// ---------------------------------------------------------------- agg: mean over each node's 19 contiguous edges
__global__ __launch_bounds__(256) void seg_mean(const bf16* __restrict__ e2,
                                                bf16* __restrict__ cat) {
    int n = blockIdx.x;
    #pragma unroll
    for (int jj = 0; jj < 2; jj++) {
        int j = threadIdx.x + jj*256;
        const bf16* base = e2 + (size_t)n*19*H_ + j;
        float s = 0.0f;
        #pragma unroll
        for (int i = 0; i < 19; i++) s += bf2f(base[(size_t)i*H_]);
        cat[(size_t)n*1024 + 512 + j] = f2bf(s / 19.0f);
    }
}

// ---------------------------------------------------------------- heads (hln lives in cat[:, :512], stride 1024)
__global__ __launch_bounds__(256) void pos_out(const bf16* __restrict__ hln,
                                               const void* __restrict__ W_coord,
                                               void* __restrict__ out,
                                               const int* __restrict__ flag) {
    int wave = threadIdx.x >> 6, lane = threadIdx.x & 63;
    int n = blockIdx.x*4 + wave;
    int isb = *flag;
    float s0 = 0, s1 = 0, s2 = 0;
    for (int k = lane; k < H_; k += 64) {
        float hv = bf2f(hln[(size_t)n*1024 + k]);
        s0 += hv * ldf(W_coord, k*3 + 0, isb);
        s1 += hv * ldf(W_coord, k*3 + 1, isb);
        s2 += hv * ldf(W_coord, k*3 + 2, isb);
    }
    for (int o = 32; o; o >>= 1) {
        s0 += __shfl_down(s0, o); s1 += __shfl_down(s1, o); s2 += __shfl_down(s2, o);
    }
    if (lane == 0) {
        if (isb) { bf16* o = (bf16*)out;  o[n*3] = f2bf(s0); o[n*3+1] = f2bf(s1); o[n*3+2] = f2bf(s2); }
        else     { float* o = (float*)out; o[n*3] = s0; o[n*3+1] = s1; o[n*3+2] = s2; }
    }
}

__global__ __launch_bounds__(512) void cell_out(const bf16* __restrict__ hln,
                                                const void* __restrict__ W_latout,
                                                const void* __restrict__ b_latout,
                                                const int* __restrict__ num_atoms,
                                                void* __restrict__ out,
                                                const int* __restrict__ flag) {
    __shared__ float red[8*6];
    int b = blockIdx.x, j = threadIdx.x;
    int isb = *flag;
    float s = 0.0f;
    for (int i = 0; i < NPG_; i++) s += bf2f(hln[(size_t)(b*NPG_ + i)*1024 + j]);
    float m = s / (float)num_atoms[b];
    float p[6];
    #pragma unroll
    for (int c = 0; c < 6; c++)
        p[c] = m * ldf(W_latout, j*6 + c, isb) + s * ldf(W_latout, (512 + j)*6 + c, isb);
    int w = j >> 6, lane = j & 63;
    #pragma unroll
    for (int c = 0; c < 6; c++) {
        float v = p[c];
        for (int o = 32; o; o >>= 1) v += __shfl_down(v, o);
        if (lane == 0) red[w*6 + c] = v;
    }
    __syncthreads();
    if (j < 6) {
        float v = 0.0f;
        for (int w2 = 0; w2 < 8; w2++) v += red[w2*6 + j];
        float r = v + ldf(b_latout, j, isb);
        if (isb) ((bf16*)out)[N_*3 + b*6 + j] = f2bf(r);
        else     ((float*)out)[N_*3 + b*6 + j] = r;
    }
}

// ================================================================ host
extern "C" void kernel_launch(void* const* d_in, const int* in_sizes, int n_in,
                              void* d_out, int out_size, void* d_ws, size_t ws_size,
                              hipStream_t stream) {
    const void* t          = d_in[0];
    const void* frac       = d_in[1];
    const void* latp       = d_in[2];
    const int*  atom_types = (const int*)d_in[3];
    const int*  num_atoms  = (const int*)d_in[4];
    const int*  node2graph = (const int*)d_in[5];
    const int*  edge_index = (const int*)d_in[6];
    const int*  e2g        = (const int*)d_in[7];
    const void* W_node     = d_in[8];
    const void* W_time     = d_in[9];
    const void* W_latent   = d_in[10];
    const void* ln_gamma   = d_in[11];
    const void* ln_beta    = d_in[12];
    const void* We1        = d_in[13];
    const void* be1        = d_in[14];
    const void* We2        = d_in[15];
    const void* be2        = d_in[16];
    const void* Wn1        = d_in[17];
    const void* bn1        = d_in[18];
    const void* Wn2        = d_in[19];
    const void* bn2        = d_in[20];
    const void* W_numatom  = d_in[21];
    const void* fln_gamma  = d_in[22];
    const void* fln_beta   = d_in[23];
    const void* W_coord    = d_in[24];
    const void* W_latout   = d_in[25];
    const void* b_latout   = d_in[26];

    // workspace carve (~101.5 MB)
    char* p = (char*)d_ws;
    auto alloc = [&](size_t bytes) { char* r = p; p += (bytes + 255) & ~(size_t)255; return r; };
    int*   flag  = (int*)alloc(4);
    float* ltl   = (float*)alloc((size_t)B_*9*4);
    float* q     = (float*)alloc((size_t)H_*4);
    float* h     = (float*)alloc((size_t)N_*H_*4);
    float* ud    = (float*)alloc((size_t)E_*3*4);
    bf16* hnAB  = (bf16*)alloc((size_t)N_*1024*2);
    bf16* femb  = (bf16*)alloc((size_t)E_*768*2);
    bf16* e1    = (bf16*)alloc((size_t)E_*H_*2);    // prep-phase alias: PQa
    bf16* e2    = (bf16*)alloc((size_t)E_*H_*2);    // prep-phase alias: PQbt
    bf16* cat   = (bf16*)alloc((size_t)N_*1024*2);
    bf16* n1s   = (bf16*)alloc((size_t)N_*H_*2);
    bf16* PQc   = (bf16*)alloc((size_t)7*128*512*2);
    bf16* WtAB  = (bf16*)alloc((size_t)1024*512*2);
    bf16* Wtf   = (bf16*)alloc((size_t)512*768*2);
    bf16* Wte2  = (bf16*)alloc((size_t)512*512*2);
    bf16* Wtn1  = (bf16*)alloc((size_t)512*1024*2);
    bf16* Wtn2  = (bf16*)alloc((size_t)512*512*2);
    bf16* PQa   = e1;
    bf16* PQbt  = e2;

    if ((size_t)(p - (char*)d_ws) > ws_size) {
        ws_sentinel<<<1, 64, 0, stream>>>((bf16*)d_out);
        return;
    }

    // ---- prep
    detect_dtype<<<1, 64, 0, stream>>>((const unsigned int*)t, flag);
    prep_graph<<<1, 64, 0, stream>>>(latp, ltl, flag);
    prep_q<<<1, 512, 0, stream>>>(W_time, W_latent, q, flag);
    pq_gather<<<dim3(7, 16), 256, 0, stream>>>(W_node, W_numatom, PQa, flag);
    transpose_pq<<<dim3(16, 16, 7), dim3(32, 8), 0, stream>>>(W_latent, We1, PQbt, flag);
    gemm_bt<0,128><<<dim3(4, 1, 7), 256, 0, stream>>>(
        PQa, 512, PQbt, nullptr, 0, PQc, nullptr, 512, 512,
        (size_t)128*512, (size_t)512*512, (size_t)128*512,
        flag, nullptr, nullptr, nullptr, nullptr, nullptr, 0, nullptr, nullptr, nullptr);
    node_embed_fast<<<N_, 512, 0, stream>>>(PQc, q, t, atom_types, node2graph, h, flag);
    edge_prep<<<E_, 384, 0, stream>>>(frac, edge_index, e2g, ltl, ud, femb, flag);

    // ---- layers
    for (size_t l = 0; l < NL_; l++) {
        transpose_layer<<<dim3(16, 32, 6), dim3(32, 8), 0, stream>>>(
            We1, We2, Wn1, Wn2, l, WtAB, Wtf, Wte2, Wtn1, Wtn2, flag);
        ln_kernel<<<N_, 256, 0, stream>>>(h, ln_gamma, ln_beta, l*H_, cat, flag);
        // hnAB = hn @ [WA|WB]
        gemm_bt<0,64><<<dim3(8, N_/64), 256, 0, stream>>>(
            cat, 1024, WtAB, nullptr, 0, hnAB, nullptr, 512, 1024, 0, 0, 0,
            flag, nullptr, nullptr, nullptr, nullptr, nullptr, 0, nullptr, nullptr, nullptr);
        // e1 = silu(femb@Wf + hnA[src] + hnB[dst] + geo + Q[na] + be1)
        gemm_bt<3,128><<<dim3(4, E_/128), 256, 0, stream>>>(
            femb, 768, Wtf, be1, l*H_, e1, nullptr, 768, 512, 0, 0, 0,
            flag, hnAB, PQc, ud, latp, We1, l, edge_index, e2g, num_atoms);
        // e2 = silu(e1@We2 + be2)
        gemm_bt<1,128><<<dim3(4, E_/128), 256, 0, stream>>>(
            e1, 512, Wte2, be2, l*H_, e2, nullptr, 512, 512, 0, 0, 0,
            flag, nullptr, nullptr, nullptr, nullptr, nullptr, 0, nullptr, nullptr, nullptr);
        seg_mean<<<N_, 256, 0, stream>>>(e2, cat);
        // n1s = silu(cat@Wn1 + bn1)
        gemm_bt<1,64><<<dim3(4, N_/64), 256, 0, stream>>>(
            cat, 1024, Wtn1, bn1, l*H_, n1s, nullptr, 1024, 512, 0, 0, 0,
            flag, nullptr, nullptr, nullptr, nullptr, nullptr, 0, nullptr, nullptr, nullptr);
        // h += silu(n1s@Wn2 + bn2)
        gemm_bt<2,64><<<dim3(4, N_/64), 256, 0, stream>>>(
            n1s, 512, Wtn2, bn2, l*H_, nullptr, h, 512, 512, 0, 0, 0,
            flag, nullptr, nullptr, nullptr, nullptr, nullptr, 0, nullptr, nullptr, nullptr);
    }

    // ---- heads
    ln_kernel<<<N_, 256, 0, stream>>>(h, fln_gamma, fln_beta, 0, cat, flag);
    pos_out<<<N_/4, 256, 0, stream>>>(cat, W_coord, d_out, flag);
    cell_out<<<B_, 512, 0, stream>>>(cat, W_latout, b_latout, num_atoms, d_out, flag);
}

// Round 6
// 1223.132 us; speedup vs baseline: 1.3902x; 1.0809x over previous
//
#include <hip/hip_runtime.h>
#include <hip/hip_bf16.h>

typedef __hip_bfloat16 bf16;
typedef __attribute__((ext_vector_type(8))) __bf16 bf16x8;
typedef __attribute__((ext_vector_type(4))) float f32x4;

#define B_   64
#define NPG_ 20
#define H_   512
#define TD_  256
#define NF_  128
#define NL_  6
#define A_   100
#define N_   (B_ * NPG_)            // 1280
#define E_   (B_ * NPG_ * (NPG_-1)) // 24320
#define EIN_ 2313

__device__ __forceinline__ float bf2f(bf16 x) { return __bfloat162float(x); }
__device__ __forceinline__ bf16  f2bf(float x) { return __float2bfloat16(x); }
__device__ __forceinline__ float siluf(float x) { return x / (1.0f + expf(-x)); }
// dual-dtype load: isb=1 -> bf16, else float32
__device__ __forceinline__ float ldf(const void* p, size_t i, int isb) {
    return isb ? bf2f(((const bf16*)p)[i]) : ((const float*)p)[i];
}
// async global->LDS, 16B/lane; HW scatters lane i to (uniform lds base) + i*16
__device__ __forceinline__ void async_cp16(const bf16* src, bf16* dst) {
    __builtin_amdgcn_global_load_lds(
        (const __attribute__((address_space(1))) unsigned int*)src,
        (__attribute__((address_space(3))) unsigned int*)dst,
        16, 0, 0);
}

// ---------------------------------------------------------------- dtype detect on t (uniform [0,1))
__global__ void detect_dtype(const unsigned int* __restrict__ tw, int* __restrict__ flag) {
    if (threadIdx.x != 0) return;
    int cnt = 0;
    for (int i = 0; i < 32; i++) {
        unsigned b1 = (tw[i] >> 8) & 0xFF;
        if (b1 >= 0x20 && b1 < 0x40) cnt++;
    }
    *flag = (cnt >= 16) ? 1 : 0;
}

__global__ void ws_sentinel(bf16* out) { if (threadIdx.x == 0) out[0] = f2bf(1000.0f); }

// ---------------------------------------------------------------- prep: lattice -> ltl (B,3,3)
__global__ void prep_graph(const void* __restrict__ latp, float* __restrict__ ltl,
                           const int* __restrict__ flag) {
    int b = threadIdx.x;
    if (b >= B_) return;
    int isb = *flag;
    const float LM[3] = {1.575442910194397f, 1.7017393112182617f, 1.9781638383865356f};
    const float LS[3] = {0.24437622725963593f, 0.26526379585266113f, 0.3535512685775757f};
    float lp[6];
    for (int i = 0; i < 6; i++) lp[i] = ldf(latp, b*6 + i, isb);
    float len[3], c[3], s[3];
    for (int i = 0; i < 3; i++) len[i] = expf(lp[i] * LS[i] + LM[i]);
    for (int i = 0; i < 3; i++) {
        float sig = 1.0f / (1.0f + expf(-lp[3+i]));
        float deg = 59.9f + 60.2f * sig;
        float a = deg * 0.017453292519943295f;
        c[i] = cosf(a); s[i] = sinf(a);
    }
    float val = (c[0]*c[1] - c[2]) / (s[0]*s[1]);
    val = fminf(1.0f, fmaxf(-1.0f, val));
    float gs = acosf(val);
    float L[3][3];
    L[0][0] = len[0]*s[1]; L[0][1] = 0.0f;               L[0][2] = len[0]*c[1];
    L[1][0] = -len[1]*s[0]*cosf(gs); L[1][1] = len[1]*s[0]*sinf(gs); L[1][2] = len[1]*c[0];
    L[2][0] = 0.0f; L[2][1] = 0.0f; L[2][2] = len[2];
    for (int i = 0; i < 3; i++)
        for (int k = 0; k < 3; k++)
            ltl[b*9 + i*3 + k] = L[i][0]*L[k][0] + L[i][1]*L[k][1] + L[i][2]*L[k][2];
}

// ---------------------------------------------------------------- prep: q[j] = sum_d W_time[d]*W_latent[512+d][j]
__global__ __launch_bounds__(512) void prep_q(const void* __restrict__ W_time,
                                              const void* __restrict__ W_latent,
                                              float* __restrict__ q,
                                              const int* __restrict__ flag) {
    int j = threadIdx.x;
    int isb = *flag;
    float s0 = 0.0f, s1 = 0.0f, s2 = 0.0f, s3 = 0.0f;
    for (int d = 0; d < TD_; d += 4) {
        s0 += ldf(W_time, d+0, isb) * ldf(W_latent, (size_t)(H_ + d+0)*H_ + j, isb);
        s1 += ldf(W_time, d+1, isb) * ldf(W_latent, (size_t)(H_ + d+1)*H_ + j, isb);
        s2 += ldf(W_time, d+2, isb) * ldf(W_latent, (size_t)(H_ + d+2)*H_ + j, isb);
        s3 += ldf(W_time, d+3, isb) * ldf(W_latent, (size_t)(H_ + d+3)*H_ + j, isb);
    }
    q[j] = (s0 + s1) + (s2 + s3);
}

// ---------------------------------------------------------------- gather A rows for PQ gemm (7 slots of 128x512)
__global__ __launch_bounds__(256) void pq_gather(const void* __restrict__ W_node,
                                                 const void* __restrict__ W_numatom,
                                                 bf16* __restrict__ PQa,
                                                 const int* __restrict__ flag) {
    int z = blockIdx.x, ch = blockIdx.y;
    int isb = *flag;
    int base = ch * 4096;
    for (int idx = base + threadIdx.x; idx < base + 4096; idx += 256) {
        int r = idx >> 9, c = idx & 511;
        float v = 0.0f;
        if (r < A_) {
            if (z == 0) v = ldf(W_node, (size_t)r*512 + c, isb);
            else        v = ldf(W_numatom, ((size_t)(z-1)*A_ + r)*512 + c, isb);
        }
        PQa[(size_t)z*65536 + idx] = f2bf(v);
    }
}

// ---------------------------------------------------------------- transpose for PQ Bt (7 slots of 512x512)
__global__ __launch_bounds__(256) void transpose_pq(const void* __restrict__ W_latent,
                                                    const void* __restrict__ We1,
                                                    bf16* __restrict__ PQbt,
                                                    const int* __restrict__ flag) {
    __shared__ bf16 tile[32][33];
    int z = blockIdx.z;
    int isb = *flag;
    const void* src = (z == 0) ? W_latent : We1;
    size_t off = (z == 0) ? 0 : ((size_t)(z-1)*EIN_ + 1801)*512;
    bf16* dst = PQbt + (size_t)z*512*512;
    int r0 = blockIdx.y * 32, c0 = blockIdx.x * 32;
    #pragma unroll
    for (int i = 0; i < 32; i += 8)
        tile[threadIdx.y + i][threadIdx.x] =
            f2bf(ldf(src, off + (size_t)(r0 + threadIdx.y + i)*512 + c0 + threadIdx.x, isb));
    __syncthreads();
    #pragma unroll
    for (int i = 0; i < 32; i += 8)
        dst[(size_t)(c0 + threadIdx.y + i)*512 + r0 + threadIdx.x] = tile[threadIdx.x][threadIdx.y + i];
}

// ---------------------------------------------------------------- per-layer weight transpose (Bt = N x K)
__global__ __launch_bounds__(256) void transpose_layer(
    const void* __restrict__ We1p, const void* __restrict__ We2p,
    const void* __restrict__ Wn1p, const void* __restrict__ Wn2p, size_t l,
    bf16* __restrict__ WtAB, bf16* __restrict__ Wtf, bf16* __restrict__ Wte2,
    bf16* __restrict__ Wtn1, bf16* __restrict__ Wtn2,
    const int* __restrict__ flag) {
    __shared__ bf16 tile[32][33];
    int which = blockIdx.z;
    int isb = *flag;
    const void* src; size_t off; bf16* dst; int R;
    switch (which) {
        case 0:  src = We1p; off = (l*EIN_ + 3)*512;    dst = WtAB;            R = 512;  break;
        case 1:  src = We1p; off = (l*EIN_ + 515)*512;  dst = WtAB + 512*512;  R = 512;  break;
        case 2:  src = We1p; off = (l*EIN_ + 1033)*512; dst = Wtf;             R = 768;  break;
        case 3:  src = We2p; off = l*512*512;           dst = Wte2;            R = 512;  break;
        case 4:  src = Wn1p; off = l*1024*512;          dst = Wtn1;            R = 1024; break;
        default: src = Wn2p; off = l*512*512;           dst = Wtn2;            R = 512;  break;
    }
    int r0 = blockIdx.y * 32, c0 = blockIdx.x * 32;
    if (r0 >= R) return;
    #pragma unroll
    for (int i = 0; i < 32; i += 8)
        tile[threadIdx.y + i][threadIdx.x] =
            f2bf(ldf(src, off + (size_t)(r0 + threadIdx.y + i)*512 + c0 + threadIdx.x, isb));
    __syncthreads();
    #pragma unroll
    for (int i = 0; i < 32; i += 8)
        dst[(size_t)(c0 + threadIdx.y + i)*R + r0 + threadIdx.x] = tile[threadIdx.x][threadIdx.y + i];
}

// ---------------------------------------------------------------- node embed: h[i][j] = P[at_i][j] + t[g]*q[j]
__global__ __launch_bounds__(512) void node_embed_fast(const bf16* __restrict__ P,
                                                       const float* __restrict__ q,
                                                       const void* __restrict__ t,
                                                       const int* __restrict__ atom_types,
                                                       const int* __restrict__ node2graph,
                                                       float* __restrict__ h,
                                                       const int* __restrict__ flag) {
    int i = blockIdx.x, j = threadIdx.x;
    int isb = *flag;
    int at = atom_types[i] - 1; if (at < 0) at = 0;
    float pv = (at < A_) ? bf2f(P[(size_t)at*512 + j]) : 0.0f;
    float tv = ldf(t, node2graph[i], isb);
    h[(size_t)i*H_ + j] = pv + tv * q[j];
}

// ---------------------------------------------------------------- edge prep: femb(bf16) + packed edat[E][16] f32
// edat: [u0,u1,u2, la0..la5, src, dst, na, pad*4] (ints stored as float bits)
__global__ __launch_bounds__(384) void edge_prep(const void* __restrict__ frac,
                                                 const int* __restrict__ edge_index,
                                                 const int* __restrict__ e2g,
                                                 const void* __restrict__ latp,
                                                 const int* __restrict__ num_atoms,
                                                 const float* __restrict__ ltl,
                                                 float* __restrict__ edat,
                                                 bf16* __restrict__ femb,
                                                 const int* __restrict__ flag) {
    const float TWO_PI_F = 6.283185307179586f;
    int e = blockIdx.x;
    int isb = *flag;
    int src = edge_index[e], dst = edge_index[E_ + e];
    int tid = threadIdx.x;
    int d = tid >> 7, k = tid & 127;
    float x = ldf(frac, src*3 + d, isb), y = ldf(frac, dst*3 + d, isb);
    float diff = y - x;
    float fd = diff - rintf(diff);
    float sv, cv;
    sincosf(fd * (TWO_PI_F * (float)k), &sv, &cv);
    femb[(size_t)e*768 + d*NF_ + k]       = f2bf(sv);
    femb[(size_t)e*768 + 384 + d*NF_ + k] = f2bf(cv);
    if (tid < 3) {
        int g = e2g[e];
        float f3[3];
        for (int dd = 0; dd < 3; dd++) {
            float df = ldf(frac, dst*3 + dd, isb) - ldf(frac, src*3 + dd, isb);
            f3[dd] = df - rintf(df);
        }
        float dots[3];
        for (int i = 0; i < 3; i++)
            dots[i] = ltl[g*9 + i*3 + 0]*f3[0] + ltl[g*9 + i*3 + 1]*f3[1] + ltl[g*9 + i*3 + 2]*f3[2];
        float nrm = sqrtf(dots[0]*dots[0] + dots[1]*dots[1] + dots[2]*dots[2]);
        edat[(size_t)e*16 + tid] = dots[tid] / (nrm + 1e-12f);
        if (tid == 0) {
            for (int i = 0; i < 6; i++) edat[(size_t)e*16 + 3 + i] = ldf(latp, g*6 + i, isb);
            int na = num_atoms[g] - 1;
            if (na < 0 || na >= A_) na = -1;
            edat[(size_t)e*16 + 9]  = __int_as_float(src);
            edat[(size_t)e*16 + 10] = __int_as_float(dst);
            edat[(size_t)e*16 + 11] = __int_as_float(na);
        }
    }
}

// ---------------------------------------------------------------- layernorm over H=512 -> cat[:, :512] (stride 1024)
__device__ __forceinline__ float block_sum_256(float v, float* red) {
    for (int o = 32; o; o >>= 1) v += __shfl_down(v, o);
    int w = threadIdx.x >> 6, lane = threadIdx.x & 63;
    if (lane == 0) red[w] = v;
    __syncthreads();
    float s = red[0] + red[1] + red[2] + red[3];
    __syncthreads();
    return s;
}

__global__ __launch_bounds__(256) void ln_kernel(const float* __restrict__ x,
                                                 const void* __restrict__ gamma,
                                                 const void* __restrict__ beta, size_t goff,
                                                 bf16* __restrict__ cat,
                                                 const int* __restrict__ flag) {
    __shared__ float red[4];
    size_t n = blockIdx.x;
    int tid = threadIdx.x;
    int isb = *flag;
    const float* xr = x + n*H_;
    float v0 = xr[tid], v1 = xr[tid + 256];
    float mu = block_sum_256(v0 + v1, red) * (1.0f/512.0f);
    float d0 = v0 - mu, d1 = v1 - mu;
    float var = block_sum_256(d0*d0 + d1*d1, red) * (1.0f/512.0f);
    float rs = 1.0f / sqrtf(var + 1e-5f);
    cat[n*1024 + tid]       = f2bf(d0*rs*ldf(gamma, goff + tid, isb)       + ldf(beta, goff + tid, isb));
    cat[n*1024 + 256 + tid] = f2bf(d1*rs*ldf(gamma, goff + tid + 256, isb) + ldf(beta, goff + tid + 256, isb));
}

// ---------------------------------------------------------------- bf16 MFMA GEMM: C(MxN) = A(MxK, lda) @ Bt(NxK)^T
// BK=64. Staging: global_load_lds 16B/lane in 8-row windows (lane = 8*ar + ac), XOR chunk
// swizzle: LDS slot (r, p) holds global chunk p^(r&7); reader p = G^(r&7), G = kk*4+lq.
// grid: x = col-blocks (fast), y = row-blocks.
// EPI: 0 = (+bias) bf16, 1 = silu bf16, 2 = Cf += silu, 3 = fused e1-assemble (uses edat)
template<int EPI, int TM>
__global__ __launch_bounds__(256) void gemm_bt(
        const bf16* __restrict__ A, int lda,
        const bf16* __restrict__ Bt,
        const void* __restrict__ bias, size_t boff,
        bf16* __restrict__ Cb, float* __restrict__ Cf,
        int K, int N,
        size_t zsA, size_t zsB, size_t zsC,
        const int* __restrict__ flag,
        const bf16* __restrict__ hnAB, const bf16* __restrict__ Qc,
        const float* __restrict__ edat,
        const void* __restrict__ We1, size_t lidx) {
    constexpr int MT = TM / 32;
    __shared__ __align__(16) bf16 As[TM*64];
    __shared__ __align__(16) bf16 Bs[128*64];
    const int z = blockIdx.z;
    A  += (size_t)z * zsA;
    Bt += (size_t)z * zsB;
    const size_t coff = (size_t)z * zsC;
    const int tid = threadIdx.x;
    const int wave = tid >> 6, lane = tid & 63;
    const int lrow = lane & 15, lq = lane >> 4;
    const size_t m0 = (size_t)blockIdx.y * TM;
    const int n0 = blockIdx.x * 128;
    const int wm = (wave >> 1) * (TM/2), wn = (wave & 1) * 64;
    const int ar = lane >> 3;          // row in 8-row window
    const int gk = (lane & 7) ^ ar;    // global 16B chunk fetched by this lane
    f32x4 acc[MT][4] = {};

    for (int k0 = 0; k0 < K; k0 += 64) {
        if (k0) __syncthreads();
        #pragma unroll
        for (int i = 0; i < TM/32; i++) {           // A windows for this wave
            int R = wave*(TM/4) + i*8;
            async_cp16(A + (m0 + R + ar)*lda + k0 + gk*8, As + R*64);
        }
        #pragma unroll
        for (int i = 0; i < 4; i++) {               // B windows
            int R = wave*32 + i*8;
            async_cp16(Bt + (size_t)(n0 + R + ar)*K + k0 + gk*8, Bs + R*64);
        }
        __syncthreads();
        #pragma unroll
        for (int kk = 0; kk < 2; kk++) {
            bf16x8 af[MT], bfr[4];
            #pragma unroll
            for (int mt = 0; mt < MT; mt++) {
                int r = wm + mt*16 + lrow;
                int p = (kk*4 + lq) ^ (r & 7);
                af[mt] = *(const bf16x8*)(As + r*64 + p*8);
            }
            #pragma unroll
            for (int nt = 0; nt < 4; nt++) {
                int r = wn + nt*16 + lrow;
                int p = (kk*4 + lq) ^ (r & 7);
                bfr[nt] = *(const bf16x8*)(Bs + r*64 + p*8);
            }
            #pragma unroll
            for (int mt = 0; mt < MT; mt++)
                #pragma unroll
                for (int nt = 0; nt < 4; nt++)
                    acc[mt][nt] = __builtin_amdgcn_mfma_f32_16x16x32_bf16(af[mt], bfr[nt], acc[mt][nt], 0, 0, 0);
        }
    }

    if constexpr (EPI == 3) {
        const int isb = *flag;
        float w9[4][9], b1v[4];
        #pragma unroll
        for (int nt = 0; nt < 4; nt++) {
            int col = n0 + wn + nt*16 + lrow;
            size_t wb = lidx*EIN_*512 + col;
            w9[nt][0] = ldf(We1, wb + 0*512, isb);
            w9[nt][1] = ldf(We1, wb + 1*512, isb);
            w9[nt][2] = ldf(We1, wb + 2*512, isb);
            #pragma unroll
            for (int i = 0; i < 6; i++) w9[nt][3+i] = ldf(We1, wb + (size_t)(1027+i)*512, isb);
            b1v[nt] = ldf(bias, boff + col, isb);
        }
        #pragma unroll
        for (int mt = 0; mt < MT; mt++) {
            #pragma unroll
            for (int r = 0; r < 4; r++) {
                size_t e = m0 + wm + mt*16 + lq*4 + r;
                const float4* ed = (const float4*)(edat + e*16);
                float4 q0 = ed[0], q1 = ed[1], q2 = ed[2];
                int se = __float_as_int(q2.y), de = __float_as_int(q2.z), na = __float_as_int(q2.w);
                #pragma unroll
                for (int nt = 0; nt < 4; nt++) {
                    int col = n0 + wn + nt*16 + lrow;
                    float x = acc[mt][nt][r] + b1v[nt]
                            + bf2f(hnAB[(size_t)se*1024 + col])
                            + bf2f(hnAB[(size_t)de*1024 + 512 + col])
                            + (na >= 0 ? bf2f(Qc[(size_t)(1+lidx)*65536 + (size_t)na*512 + col]) : 0.0f)
                            + q0.x*w9[nt][0] + q0.y*w9[nt][1] + q0.z*w9[nt][2]
                            + q0.w*w9[nt][3] + q1.x*w9[nt][4] + q1.y*w9[nt][5]
                            + q1.z*w9[nt][6] + q1.w*w9[nt][7] + q2.x*w9[nt][8];
                    Cb[e*512 + col] = f2bf(siluf(x));
                }
            }
        }
    } else {
        const int isb = bias ? *flag : 0;
        #pragma unroll
        for (int mt = 0; mt < MT; mt++)
            #pragma unroll
            for (int nt = 0; nt < 4; nt++) {
                int col = n0 + wn + nt*16 + lrow;
                float bv = bias ? ldf(bias, boff + col, isb) : 0.0f;
                #pragma unroll
                for (int r = 0; r < 4; r++) {
                    size_t row = m0 + wm + mt*16 + lq*4 + r;
                    float x = acc[mt][nt][r] + bv;
                    if (EPI == 0)      Cb[coff + row*N + col] = f2bf(x);
                    else if (EPI == 1) Cb[coff + row*N + col] = f2bf(siluf(x));
                    else               Cf[coff + row*N + col] += siluf(x);
                }
            }
    }
}

// ---------------------------------------------------------------- agg: mean over each node's 19 contiguous edges
__global__ __launch_bounds__(256) void seg_mean(const bf16* __restrict__ e2,
                                                bf16* __restrict__ cat) {
    int n = blockIdx.x;
    #pragma unroll
    for (int jj = 0; jj < 2; jj++) {
        int j = threadIdx.x + jj*256;
        const bf16* base = e2 + (size_t)n*19*H_ + j;
        float s = 0.0f;
        #pragma unroll
        for (int i = 0; i < 19; i++) s += bf2f(base[(size_t)i*H_]);
        cat[(size_t)n*1024 + 512 + j] = f2bf(s / 19.0f);
    }
}

// ---------------------------------------------------------------- heads (hln lives in cat[:, :512], stride 1024)
__global__ __launch_bounds__(256) void pos_out(const bf16* __restrict__ hln,
                                               const void* __restrict__ W_coord,
                                               void* __restrict__ out,
                                               const int* __restrict__ flag) {
    int wave = threadIdx.x >> 6, lane = threadIdx.x & 63;
    int n = blockIdx.x*4 + wave;
    int isb = *flag;
    float s0 = 0, s1 = 0, s2 = 0;
    for (int k = lane; k < H_; k += 64) {
        float hv = bf2f(hln[(size_t)n*1024 + k]);
        s0 += hv * ldf(W_coord, k*3 + 0, isb);
        s1 += hv * ldf(W_coord, k*3 + 1, isb);
        s2 += hv * ldf(W_coord, k*3 + 2, isb);
    }
    for (int o = 32; o; o >>= 1) {
        s0 += __shfl_down(s0, o); s1 += __shfl_down(s1, o); s2 += __shfl_down(s2, o);
    }
    if (lane == 0) {
        if (isb) { bf16* o = (bf16*)out;  o[n*3] = f2bf(s0); o[n*3+1] = f2bf(s1); o[n*3+2] = f2bf(s2); }
        else     { float* o = (float*)out; o[n*3] = s0; o[n*3+1] = s1; o[n*3+2] = s2; }
    }
}

__global__ __launch_bounds__(512) void cell_out(const bf16* __restrict__ hln,
                                                const void* __restrict__ W_latout,
                                                const void* __restrict__ b_latout,
                                                const int* __restrict__ num_atoms,
                                                void* __restrict__ out,
                                                const int* __restrict__ flag) {
    __shared__ float red[8*6];
    int b = blockIdx.x, j = threadIdx.x;
    int isb = *flag;
    float s = 0.0f;
    for (int i = 0; i < NPG_; i++) s += bf2f(hln[(size_t)(b*NPG_ + i)*1024 + j]);
    float m = s / (float)num_atoms[b];
    float p[6];
    #pragma unroll
    for (int c = 0; c < 6; c++)
        p[c] = m * ldf(W_latout, j*6 + c, isb) + s * ldf(W_latout, (512 + j)*6 + c, isb);
    int w = j >> 6, lane = j & 63;
    #pragma unroll
    for (int c = 0; c < 6; c++) {
        float v = p[c];
        for (int o = 32; o; o >>= 1) v += __shfl_down(v, o);
        if (lane == 0) red[w*6 + c] = v;
    }
    __syncthreads();
    if (j < 6) {
        float v = 0.0f;
        for (int w2 = 0; w2 < 8; w2++) v += red[w2*6 + j];
        float r = v + ldf(b_latout, j, isb);
        if (isb) ((bf16*)out)[N_*3 + b*6 + j] = f2bf(r);
        else     ((float*)out)[N_*3 + b*6 + j] = r;
    }
}

// ================================================================ host
extern "C" void kernel_launch(void* const* d_in, const int* in_sizes, int n_in,
                              void* d_out, int out_size, void* d_ws, size_t ws_size,
                              hipStream_t stream) {
    const void* t          = d_in[0];
    const void* frac       = d_in[1];
    const void* latp       = d_in[2];
    const int*  atom_types = (const int*)d_in[3];
    const int*  num_atoms  = (const int*)d_in[4];
    const int*  node2graph = (const int*)d_in[5];
    const int*  edge_index = (const int*)d_in[6];
    const int*  e2g        = (const int*)d_in[7];
    const void* W_node     = d_in[8];
    const void* W_time     = d_in[9];
    const void* W_latent   = d_in[10];
    const void* ln_gamma   = d_in[11];
    const void* ln_beta    = d_in[12];
    const void* We1        = d_in[13];
    const void* be1        = d_in[14];
    const void* We2        = d_in[15];
    const void* be2        = d_in[16];
    const void* Wn1        = d_in[17];
    const void* bn1        = d_in[18];
    const void* Wn2        = d_in[19];
    const void* bn2        = d_in[20];
    const void* W_numatom  = d_in[21];
    const void* fln_gamma  = d_in[22];
    const void* fln_beta   = d_in[23];
    const void* W_coord    = d_in[24];
    const void* W_latout   = d_in[25];
    const void* b_latout   = d_in[26];

    // workspace carve (~103 MB)
    char* p = (char*)d_ws;
    auto alloc = [&](size_t bytes) { char* r = p; p += (bytes + 255) & ~(size_t)255; return r; };
    int*   flag  = (int*)alloc(4);
    float* ltl   = (float*)alloc((size_t)B_*9*4);
    float* q     = (float*)alloc((size_t)H_*4);
    float* h     = (float*)alloc((size_t)N_*H_*4);
    float* edat  = (float*)alloc((size_t)E_*16*4);
    bf16* hnAB  = (bf16*)alloc((size_t)N_*1024*2);
    bf16* femb  = (bf16*)alloc((size_t)E_*768*2);
    bf16* e1    = (bf16*)alloc((size_t)E_*H_*2);    // prep-phase alias: PQa
    bf16* e2    = (bf16*)alloc((size_t)E_*H_*2);    // prep-phase alias: PQbt
    bf16* cat   = (bf16*)alloc((size_t)N_*1024*2);
    bf16* n1s   = (bf16*)alloc((size_t)N_*H_*2);
    bf16* PQc   = (bf16*)alloc((size_t)7*128*512*2);
    bf16* WtAB  = (bf16*)alloc((size_t)1024*512*2);
    bf16* Wtf   = (bf16*)alloc((size_t)512*768*2);
    bf16* Wte2  = (bf16*)alloc((size_t)512*512*2);
    bf16* Wtn1  = (bf16*)alloc((size_t)512*1024*2);
    bf16* Wtn2  = (bf16*)alloc((size_t)512*512*2);
    bf16* PQa   = e1;
    bf16* PQbt  = e2;

    if ((size_t)(p - (char*)d_ws) > ws_size) {
        ws_sentinel<<<1, 64, 0, stream>>>((bf16*)d_out);
        return;
    }

    // ---- prep
    detect_dtype<<<1, 64, 0, stream>>>((const unsigned int*)t, flag);
    prep_graph<<<1, 64, 0, stream>>>(latp, ltl, flag);
    prep_q<<<1, 512, 0, stream>>>(W_time, W_latent, q, flag);
    pq_gather<<<dim3(7, 16), 256, 0, stream>>>(W_node, W_numatom, PQa, flag);
    transpose_pq<<<dim3(16, 16, 7), dim3(32, 8), 0, stream>>>(W_latent, We1, PQbt, flag);
    gemm_bt<0,128><<<dim3(4, 1, 7), 256, 0, stream>>>(
        PQa, 512, PQbt, nullptr, 0, PQc, nullptr, 512, 512,
        (size_t)128*512, (size_t)512*512, (size_t)128*512,
        flag, nullptr, nullptr, nullptr, nullptr, 0);
    node_embed_fast<<<N_, 512, 0, stream>>>(PQc, q, t, atom_types, node2graph, h, flag);
    edge_prep<<<E_, 384, 0, stream>>>(frac, edge_index, e2g, latp, num_atoms, ltl, edat, femb, flag);

    // ---- layers
    for (size_t l = 0; l < NL_; l++) {
        transpose_layer<<<dim3(16, 32, 6), dim3(32, 8), 0, stream>>>(
            We1, We2, Wn1, Wn2, l, WtAB, Wtf, Wte2, Wtn1, Wtn2, flag);
        ln_kernel<<<N_, 256, 0, stream>>>(h, ln_gamma, ln_beta, l*H_, cat, flag);
        // hnAB = hn @ [WA|WB]
        gemm_bt<0,64><<<dim3(8, N_/64), 256, 0, stream>>>(
            cat, 1024, WtAB, nullptr, 0, hnAB, nullptr, 512, 1024, 0, 0, 0,
            flag, nullptr, nullptr, nullptr, nullptr, 0);
        // e1 = silu(femb@Wf + hnA[src] + hnB[dst] + geo + Q[na] + be1)
        gemm_bt<3,128><<<dim3(4, E_/128), 256, 0, stream>>>(
            femb, 768, Wtf, be1, l*H_, e1, nullptr, 768, 512, 0, 0, 0,
            flag, hnAB, PQc, edat, We1, l);
        // e2 = silu(e1@We2 + be2)
        gemm_bt<1,128><<<dim3(4, E_/128), 256, 0, stream>>>(
            e1, 512, Wte2, be2, l*H_, e2, nullptr, 512, 512, 0, 0, 0,
            flag, nullptr, nullptr, nullptr, nullptr, 0);
        seg_mean<<<N_, 256, 0, stream>>>(e2, cat);
        // n1s = silu(cat@Wn1 + bn1)
        gemm_bt<1,64><<<dim3(4, N_/64), 256, 0, stream>>>(
            cat, 1024, Wtn1, bn1, l*H_, n1s, nullptr, 1024, 512, 0, 0, 0,
            flag, nullptr, nullptr, nullptr, nullptr, 0);
        // h += silu(n1s@Wn2 + bn2)
        gemm_bt<2,64><<<dim3(4, N_/64), 256, 0, stream>>>(
            n1s, 512, Wtn2, bn2, l*H_, nullptr, h, 512, 512, 0, 0, 0,
            flag, nullptr, nullptr, nullptr, nullptr, 0);
    }

    // ---- heads
    ln_kernel<<<N_, 256, 0, stream>>>(h, fln_gamma, fln_beta, 0, cat, flag);
    pos_out<<<N_/4, 256, 0, stream>>>(cat, W_coord, d_out, flag);
    cell_out<<<B_, 512, 0, stream>>>(cat, W_latout, b_latout, num_atoms, d_out, flag);
}

// Round 7
// 1189.374 us; speedup vs baseline: 1.4297x; 1.0284x over previous
//
#include <hip/hip_runtime.h>
#include <hip/hip_bf16.h>

typedef __hip_bfloat16 bf16;
typedef __attribute__((ext_vector_type(8))) __bf16 bf16x8;
typedef __attribute__((ext_vector_type(4))) float f32x4;

#define B_   64
#define NPG_ 20
#define H_   512
#define TD_  256
#define NF_  128
#define NL_  6
#define A_   100
#define N_   (B_ * NPG_)            // 1280
#define E_   (B_ * NPG_ * (NPG_-1)) // 24320
#define EIN_ 2313
#define KF_  832                     // 768 femb + 9 geo + 55 zero-pad

__device__ __forceinline__ float bf2f(bf16 x) { return __bfloat162float(x); }
__device__ __forceinline__ bf16  f2bf(float x) { return __float2bfloat16(x); }
__device__ __forceinline__ float siluf(float x) { return x / (1.0f + expf(-x)); }
// dual-dtype load: isb=1 -> bf16, else float32
__device__ __forceinline__ float ldf(const void* p, size_t i, int isb) {
    return isb ? bf2f(((const bf16*)p)[i]) : ((const float*)p)[i];
}
// async global->LDS, 16B/lane; HW scatters lane i to (uniform lds base) + i*16
__device__ __forceinline__ void async_cp16(const bf16* src, bf16* dst) {
    __builtin_amdgcn_global_load_lds(
        (const __attribute__((address_space(1))) unsigned int*)src,
        (__attribute__((address_space(3))) unsigned int*)dst,
        16, 0, 0);
}

// ---------------------------------------------------------------- dtype detect on t (uniform [0,1))
__global__ void detect_dtype(const unsigned int* __restrict__ tw, int* __restrict__ flag) {
    if (threadIdx.x != 0) return;
    int cnt = 0;
    for (int i = 0; i < 32; i++) {
        unsigned b1 = (tw[i] >> 8) & 0xFF;
        if (b1 >= 0x20 && b1 < 0x40) cnt++;
    }
    *flag = (cnt >= 16) ? 1 : 0;
}

__global__ void ws_sentinel(bf16* out) { if (threadIdx.x == 0) out[0] = f2bf(1000.0f); }

// ---------------------------------------------------------------- prep: lattice -> ltl (B,3,3)
__global__ void prep_graph(const void* __restrict__ latp, float* __restrict__ ltl,
                           const int* __restrict__ flag) {
    int b = threadIdx.x;
    if (b >= B_) return;
    int isb = *flag;
    const float LM[3] = {1.575442910194397f, 1.7017393112182617f, 1.9781638383865356f};
    const float LS[3] = {0.24437622725963593f, 0.26526379585266113f, 0.3535512685775757f};
    float lp[6];
    for (int i = 0; i < 6; i++) lp[i] = ldf(latp, b*6 + i, isb);
    float len[3], c[3], s[3];
    for (int i = 0; i < 3; i++) len[i] = expf(lp[i] * LS[i] + LM[i]);
    for (int i = 0; i < 3; i++) {
        float sig = 1.0f / (1.0f + expf(-lp[3+i]));
        float deg = 59.9f + 60.2f * sig;
        float a = deg * 0.017453292519943295f;
        c[i] = cosf(a); s[i] = sinf(a);
    }
    float val = (c[0]*c[1] - c[2]) / (s[0]*s[1]);
    val = fminf(1.0f, fmaxf(-1.0f, val));
    float gs = acosf(val);
    float L[3][3];
    L[0][0] = len[0]*s[1]; L[0][1] = 0.0f;               L[0][2] = len[0]*c[1];
    L[1][0] = -len[1]*s[0]*cosf(gs); L[1][1] = len[1]*s[0]*sinf(gs); L[1][2] = len[1]*c[0];
    L[2][0] = 0.0f; L[2][1] = 0.0f; L[2][2] = len[2];
    for (int i = 0; i < 3; i++)
        for (int k = 0; k < 3; k++)
            ltl[b*9 + i*3 + k] = L[i][0]*L[k][0] + L[i][1]*L[k][1] + L[i][2]*L[k][2];
}

// ---------------------------------------------------------------- prep: q[j] = sum_d W_time[d]*W_latent[512+d][j]
__global__ __launch_bounds__(512) void prep_q(const void* __restrict__ W_time,
                                              const void* __restrict__ W_latent,
                                              float* __restrict__ q,
                                              const int* __restrict__ flag) {
    int j = threadIdx.x;
    int isb = *flag;
    float s0 = 0.0f, s1 = 0.0f, s2 = 0.0f, s3 = 0.0f;
    for (int d = 0; d < TD_; d += 4) {
        s0 += ldf(W_time, d+0, isb) * ldf(W_latent, (size_t)(H_ + d+0)*H_ + j, isb);
        s1 += ldf(W_time, d+1, isb) * ldf(W_latent, (size_t)(H_ + d+1)*H_ + j, isb);
        s2 += ldf(W_time, d+2, isb) * ldf(W_latent, (size_t)(H_ + d+2)*H_ + j, isb);
        s3 += ldf(W_time, d+3, isb) * ldf(W_latent, (size_t)(H_ + d+3)*H_ + j, isb);
    }
    q[j] = (s0 + s1) + (s2 + s3);
}

// ---------------------------------------------------------------- gather A rows for PQ gemm (7 slots of 128x512)
__global__ __launch_bounds__(256) void pq_gather(const void* __restrict__ W_node,
                                                 const void* __restrict__ W_numatom,
                                                 bf16* __restrict__ PQa,
                                                 const int* __restrict__ flag) {
    int z = blockIdx.x, ch = blockIdx.y;
    int isb = *flag;
    int base = ch * 4096;
    for (int idx = base + threadIdx.x; idx < base + 4096; idx += 256) {
        int r = idx >> 9, c = idx & 511;
        float v = 0.0f;
        if (r < A_) {
            if (z == 0) v = ldf(W_node, (size_t)r*512 + c, isb);
            else        v = ldf(W_numatom, ((size_t)(z-1)*A_ + r)*512 + c, isb);
        }
        PQa[(size_t)z*65536 + idx] = f2bf(v);
    }
}

// ---------------------------------------------------------------- transpose for PQ Bt (7 slots of 512x512)
__global__ __launch_bounds__(256) void transpose_pq(const void* __restrict__ W_latent,
                                                    const void* __restrict__ We1,
                                                    bf16* __restrict__ PQbt,
                                                    const int* __restrict__ flag) {
    __shared__ bf16 tile[32][33];
    int z = blockIdx.z;
    int isb = *flag;
    const void* src = (z == 0) ? W_latent : We1;
    size_t off = (z == 0) ? 0 : ((size_t)(z-1)*EIN_ + 1801)*512;
    bf16* dst = PQbt + (size_t)z*512*512;
    int r0 = blockIdx.y * 32, c0 = blockIdx.x * 32;
    #pragma unroll
    for (int i = 0; i < 32; i += 8)
        tile[threadIdx.y + i][threadIdx.x] =
            f2bf(ldf(src, off + (size_t)(r0 + threadIdx.y + i)*512 + c0 + threadIdx.x, isb));
    __syncthreads();
    #pragma unroll
    for (int i = 0; i < 32; i += 8)
        dst[(size_t)(c0 + threadIdx.y + i)*512 + r0 + threadIdx.x] = tile[threadIdx.x][threadIdx.y + i];
}

// ---------------------------------------------------------------- per-layer weight transpose (Bt = N x K)
__global__ __launch_bounds__(256) void transpose_layer(
    const void* __restrict__ We1p, const void* __restrict__ We2p,
    const void* __restrict__ Wn1p, const void* __restrict__ Wn2p, size_t l,
    bf16* __restrict__ WtAB, bf16* __restrict__ Wtf, bf16* __restrict__ Wte2,
    bf16* __restrict__ Wtn1, bf16* __restrict__ Wtn2,
    const int* __restrict__ flag) {
    __shared__ bf16 tile[32][33];
    int which = blockIdx.z;
    int isb = *flag;
    const void* src; size_t off; bf16* dst; int R; int ldd;
    switch (which) {
        case 0:  src = We1p; off = (l*EIN_ + 3)*512;    dst = WtAB;            R = 512;  ldd = 512;  break;
        case 1:  src = We1p; off = (l*EIN_ + 515)*512;  dst = WtAB + 512*512;  R = 512;  ldd = 512;  break;
        case 2:  src = We1p; off = (l*EIN_ + 1033)*512; dst = Wtf;             R = 768;  ldd = KF_;  break;
        case 3:  src = We2p; off = l*512*512;           dst = Wte2;            R = 512;  ldd = 512;  break;
        case 4:  src = Wn1p; off = l*1024*512;          dst = Wtn1;            R = 1024; ldd = 1024; break;
        default: src = Wn2p; off = l*512*512;           dst = Wtn2;            R = 512;  ldd = 512;  break;
    }
    int r0 = blockIdx.y * 32, c0 = blockIdx.x * 32;
    if (r0 >= R) return;
    #pragma unroll
    for (int i = 0; i < 32; i += 8)
        tile[threadIdx.y + i][threadIdx.x] =
            f2bf(ldf(src, off + (size_t)(r0 + threadIdx.y + i)*512 + c0 + threadIdx.x, isb));
    __syncthreads();
    #pragma unroll
    for (int i = 0; i < 32; i += 8)
        dst[(size_t)(c0 + threadIdx.y + i)*ldd + r0 + threadIdx.x] = tile[threadIdx.x][threadIdx.y + i];
}

// ---------------------------------------------------------------- Wtf tail: cols 768..831 = 9 geometry rows of We1, else 0
__global__ __launch_bounds__(512) void wtf_tail(const void* __restrict__ We1, size_t l,
                                                bf16* __restrict__ Wtf,
                                                const int* __restrict__ flag) {
    int n = threadIdx.x;
    int isb = *flag;
    const int rows[9] = {0, 1, 2, 1027, 1028, 1029, 1030, 1031, 1032};
    #pragma unroll
    for (int j = 0; j < 64; j++) {
        float v = (j < 9) ? ldf(We1, (l*EIN_ + rows[j])*512 + n, isb) : 0.0f;
        Wtf[(size_t)n*KF_ + 768 + j] = f2bf(v);
    }
}

// ---------------------------------------------------------------- node embed: h[i][j] = P[at_i][j] + t[g]*q[j]
__global__ __launch_bounds__(512) void node_embed_fast(const bf16* __restrict__ P,
                                                       const float* __restrict__ q,
                                                       const void* __restrict__ t,
                                                       const int* __restrict__ atom_types,
                                                       const int* __restrict__ node2graph,
                                                       float* __restrict__ h,
                                                       const int* __restrict__ flag) {
    int i = blockIdx.x, j = threadIdx.x;
    int isb = *flag;
    int at = atom_types[i] - 1; if (at < 0) at = 0;
    float pv = (at < A_) ? bf2f(P[(size_t)at*512 + j]) : 0.0f;
    float tv = ldf(t, node2graph[i], isb);
    h[(size_t)i*H_ + j] = pv + tv * q[j];
}

// ---------------------------------------------------------------- edge prep: femb(E x 832 bf16) + edat[E][4] int
// femb cols: [0:384) sin, [384:768) cos, [768:777) = (u0,u1,u2, la0..la5), [777:832) = 0
__global__ __launch_bounds__(384) void edge_prep(const void* __restrict__ frac,
                                                 const int* __restrict__ edge_index,
                                                 const int* __restrict__ e2g,
                                                 const void* __restrict__ latp,
                                                 const int* __restrict__ num_atoms,
                                                 const float* __restrict__ ltl,
                                                 int* __restrict__ edat,
                                                 bf16* __restrict__ femb,
                                                 const int* __restrict__ flag) {
    const float TWO_PI_F = 6.283185307179586f;
    int e = blockIdx.x;
    int isb = *flag;
    int src = edge_index[e], dst = edge_index[E_ + e];
    int tid = threadIdx.x;
    int d = tid >> 7, k = tid & 127;
    float x = ldf(frac, src*3 + d, isb), y = ldf(frac, dst*3 + d, isb);
    float diff = y - x;
    float fd = diff - rintf(diff);
    float sv, cv;
    sincosf(fd * (TWO_PI_F * (float)k), &sv, &cv);
    femb[(size_t)e*KF_ + d*NF_ + k]       = f2bf(sv);
    femb[(size_t)e*KF_ + 384 + d*NF_ + k] = f2bf(cv);
    if (tid < 64) {
        int g = e2g[e];
        float v = 0.0f;
        if (tid < 3) {
            float f3[3];
            for (int dd = 0; dd < 3; dd++) {
                float df = ldf(frac, dst*3 + dd, isb) - ldf(frac, src*3 + dd, isb);
                f3[dd] = df - rintf(df);
            }
            float dots[3];
            for (int i = 0; i < 3; i++)
                dots[i] = ltl[g*9 + i*3 + 0]*f3[0] + ltl[g*9 + i*3 + 1]*f3[1] + ltl[g*9 + i*3 + 2]*f3[2];
            float nrm = sqrtf(dots[0]*dots[0] + dots[1]*dots[1] + dots[2]*dots[2]);
            v = dots[tid] / (nrm + 1e-12f);
        } else if (tid < 9) {
            v = ldf(latp, g*6 + tid - 3, isb);
        }
        femb[(size_t)e*KF_ + 768 + tid] = f2bf(v);
        if (tid == 0) {
            int na = num_atoms[g] - 1;
            if (na < 0 || na >= A_) na = -1;
            edat[e*4 + 0] = src;
            edat[e*4 + 1] = dst;
            edat[e*4 + 2] = na;
            edat[e*4 + 3] = 0;
        }
    }
}

// ---------------------------------------------------------------- layernorm over H=512 -> cat[:, :512] (stride 1024)
__device__ __forceinline__ float block_sum_256(float v, float* red) {
    for (int o = 32; o; o >>= 1) v += __shfl_down(v, o);
    int w = threadIdx.x >> 6, lane = threadIdx.x & 63;
    if (lane == 0) red[w] = v;
    __syncthreads();
    float s = red[0] + red[1] + red[2] + red[3];
    __syncthreads();
    return s;
}

__global__ __launch_bounds__(256) void ln_kernel(const float* __restrict__ x,
                                                 const void* __restrict__ gamma,
                                                 const void* __restrict__ beta, size_t goff,
                                                 bf16* __restrict__ cat,
                                                 const int* __restrict__ flag) {
    __shared__ float red[4];
    size_t n = blockIdx.x;
    int tid = threadIdx.x;
    int isb = *flag;
    const float* xr = x + n*H_;
    float v0 = xr[tid], v1 = xr[tid + 256];
    float mu = block_sum_256(v0 + v1, red) * (1.0f/512.0f);
    float d0 = v0 - mu, d1 = v1 - mu;
    float var = block_sum_256(d0*d0 + d1*d1, red) * (1.0f/512.0f);
    float rs = 1.0f / sqrtf(var + 1e-5f);
    cat[n*1024 + tid]       = f2bf(d0*rs*ldf(gamma, goff + tid, isb)       + ldf(beta, goff + tid, isb));
    cat[n*1024 + 256 + tid] = f2bf(d1*rs*ldf(gamma, goff + tid + 256, isb) + ldf(beta, goff + tid + 256, isb));
}

// ---------------------------------------------------------------- bf16 MFMA GEMM: C(MxN) = A(MxK, lda) @ Bt(NxK)^T
// BK=64, async global_load_lds staging with XOR chunk swizzle (conflict-free, verified R5).
// grid: x = col-blocks (fast), y = row-blocks.
// EPI: 0 = (+bias) bf16, 1 = silu bf16, 2 = Cf += silu, 3 = e1-assemble (gathers only; geo folded into K)
template<int EPI, int TM>
__global__ __launch_bounds__(256) void gemm_bt(
        const bf16* __restrict__ A, int lda,
        const bf16* __restrict__ Bt,
        const void* __restrict__ bias, size_t boff,
        bf16* __restrict__ Cb, float* __restrict__ Cf,
        int K, int N,
        size_t zsA, size_t zsB, size_t zsC,
        const int* __restrict__ flag,
        const bf16* __restrict__ hnAB, const bf16* __restrict__ Qc,
        const int* __restrict__ edat, size_t lidx) {
    constexpr int MT = TM / 32;
    __shared__ __align__(16) bf16 As[TM*64];
    __shared__ __align__(16) bf16 Bs[128*64];
    const int z = blockIdx.z;
    A  += (size_t)z * zsA;
    Bt += (size_t)z * zsB;
    const size_t coff = (size_t)z * zsC;
    const int tid = threadIdx.x;
    const int wave = tid >> 6, lane = tid & 63;
    const int lrow = lane & 15, lq = lane >> 4;
    const size_t m0 = (size_t)blockIdx.y * TM;
    const int n0 = blockIdx.x * 128;
    const int wm = (wave >> 1) * (TM/2), wn = (wave & 1) * 64;
    const int ar = lane >> 3;          // row in 8-row window
    const int gk = (lane & 7) ^ ar;    // global 16B chunk fetched by this lane
    f32x4 acc[MT][4] = {};

    for (int k0 = 0; k0 < K; k0 += 64) {
        if (k0) __syncthreads();
        #pragma unroll
        for (int i = 0; i < TM/32; i++) {           // A windows for this wave
            int R = wave*(TM/4) + i*8;
            async_cp16(A + (m0 + R + ar)*lda + k0 + gk*8, As + R*64);
        }
        #pragma unroll
        for (int i = 0; i < 4; i++) {               // B windows
            int R = wave*32 + i*8;
            async_cp16(Bt + (size_t)(n0 + R + ar)*K + k0 + gk*8, Bs + R*64);
        }
        __syncthreads();
        #pragma unroll
        for (int kk = 0; kk < 2; kk++) {
            bf16x8 af[MT], bfr[4];
            #pragma unroll
            for (int mt = 0; mt < MT; mt++) {
                int r = wm + mt*16 + lrow;
                int p = (kk*4 + lq) ^ (r & 7);
                af[mt] = *(const bf16x8*)(As + r*64 + p*8);
            }
            #pragma unroll
            for (int nt = 0; nt < 4; nt++) {
                int r = wn + nt*16 + lrow;
                int p = (kk*4 + lq) ^ (r & 7);
                bfr[nt] = *(const bf16x8*)(Bs + r*64 + p*8);
            }
            #pragma unroll
            for (int mt = 0; mt < MT; mt++)
                #pragma unroll
                for (int nt = 0; nt < 4; nt++)
                    acc[mt][nt] = __builtin_amdgcn_mfma_f32_16x16x32_bf16(af[mt], bfr[nt], acc[mt][nt], 0, 0, 0);
        }
    }

    if constexpr (EPI == 3) {
        const int isb = *flag;
        float b1v[4];
        #pragma unroll
        for (int nt = 0; nt < 4; nt++)
            b1v[nt] = ldf(bias, boff + n0 + wn + nt*16 + lrow, isb);
        #pragma unroll
        for (int mt = 0; mt < MT; mt++) {
            #pragma unroll
            for (int r = 0; r < 4; r++) {
                size_t e = m0 + wm + mt*16 + lq*4 + r;
                const int4 q = *(const int4*)(edat + e*4);
                int se = q.x, de = q.y, na = q.z;
                #pragma unroll
                for (int nt = 0; nt < 4; nt++) {
                    int col = n0 + wn + nt*16 + lrow;
                    float x = acc[mt][nt][r] + b1v[nt]
                            + bf2f(hnAB[(size_t)se*1024 + col])
                            + bf2f(hnAB[(size_t)de*1024 + 512 + col])
                            + (na >= 0 ? bf2f(Qc[(size_t)(1+lidx)*65536 + (size_t)na*512 + col]) : 0.0f);
                    Cb[e*512 + col] = f2bf(siluf(x));
                }
            }
        }
    } else {
        const int isb = bias ? *flag : 0;
        #pragma unroll
        for (int mt = 0; mt < MT; mt++)
            #pragma unroll
            for (int nt = 0; nt < 4; nt++) {
                int col = n0 + wn + nt*16 + lrow;
                float bv = bias ? ldf(bias, boff + col, isb) : 0.0f;
                #pragma unroll
                for (int r = 0; r < 4; r++) {
                    size_t row = m0 + wm + mt*16 + lq*4 + r;
                    float x = acc[mt][nt][r] + bv;
                    if (EPI == 0)      Cb[coff + row*N + col] = f2bf(x);
                    else if (EPI == 1) Cb[coff + row*N + col] = f2bf(siluf(x));
                    else               Cf[coff + row*N + col] += siluf(x);
                }
            }
    }
}

// ---------------------------------------------------------------- agg: mean over each node's 19 contiguous edges
__global__ __launch_bounds__(256) void seg_mean(const bf16* __restrict__ e2,
                                                bf16* __restrict__ cat) {
    int n = blockIdx.x;
    #pragma unroll
    for (int jj = 0; jj < 2; jj++) {
        int j = threadIdx.x + jj*256;
        const bf16* base = e2 + (size_t)n*19*H_ + j;
        float s = 0.0f;
        #pragma unroll
        for (int i = 0; i < 19; i++) s += bf2f(base[(size_t)i*H_]);
        cat[(size_t)n*1024 + 512 + j] = f2bf(s / 19.0f);
    }
}

// ---------------------------------------------------------------- heads (hln lives in cat[:, :512], stride 1024)
__global__ __launch_bounds__(256) void pos_out(const bf16* __restrict__ hln,
                                               const void* __restrict__ W_coord,
                                               void* __restrict__ out,
                                               const int* __restrict__ flag) {
    int wave = threadIdx.x >> 6, lane = threadIdx.x & 63;
    int n = blockIdx.x*4 + wave;
    int isb = *flag;
    float s0 = 0, s1 = 0, s2 = 0;
    for (int k = lane; k < H_; k += 64) {
        float hv = bf2f(hln[(size_t)n*1024 + k]);
        s0 += hv * ldf(W_coord, k*3 + 0, isb);
        s1 += hv * ldf(W_coord, k*3 + 1, isb);
        s2 += hv * ldf(W_coord, k*3 + 2, isb);
    }
    for (int o = 32; o; o >>= 1) {
        s0 += __shfl_down(s0, o); s1 += __shfl_down(s1, o); s2 += __shfl_down(s2, o);
    }
    if (lane == 0) {
        if (isb) { bf16* o = (bf16*)out;  o[n*3] = f2bf(s0); o[n*3+1] = f2bf(s1); o[n*3+2] = f2bf(s2); }
        else     { float* o = (float*)out; o[n*3] = s0; o[n*3+1] = s1; o[n*3+2] = s2; }
    }
}

__global__ __launch_bounds__(512) void cell_out(const bf16* __restrict__ hln,
                                                const void* __restrict__ W_latout,
                                                const void* __restrict__ b_latout,
                                                const int* __restrict__ num_atoms,
                                                void* __restrict__ out,
                                                const int* __restrict__ flag) {
    __shared__ float red[8*6];
    int b = blockIdx.x, j = threadIdx.x;
    int isb = *flag;
    float s = 0.0f;
    for (int i = 0; i < NPG_; i++) s += bf2f(hln[(size_t)(b*NPG_ + i)*1024 + j]);
    float m = s / (float)num_atoms[b];
    float p[6];
    #pragma unroll
    for (int c = 0; c < 6; c++)
        p[c] = m * ldf(W_latout, j*6 + c, isb) + s * ldf(W_latout, (512 + j)*6 + c, isb);
    int w = j >> 6, lane = j & 63;
    #pragma unroll
    for (int c = 0; c < 6; c++) {
        float v = p[c];
        for (int o = 32; o; o >>= 1) v += __shfl_down(v, o);
        if (lane == 0) red[w*6 + c] = v;
    }
    __syncthreads();
    if (j < 6) {
        float v = 0.0f;
        for (int w2 = 0; w2 < 8; w2++) v += red[w2*6 + j];
        float r = v + ldf(b_latout, j, isb);
        if (isb) ((bf16*)out)[N_*3 + b*6 + j] = f2bf(r);
        else     ((float*)out)[N_*3 + b*6 + j] = r;
    }
}

// ================================================================ host
extern "C" void kernel_launch(void* const* d_in, const int* in_sizes, int n_in,
                              void* d_out, int out_size, void* d_ws, size_t ws_size,
                              hipStream_t stream) {
    const void* t          = d_in[0];
    const void* frac       = d_in[1];
    const void* latp       = d_in[2];
    const int*  atom_types = (const int*)d_in[3];
    const int*  num_atoms  = (const int*)d_in[4];
    const int*  node2graph = (const int*)d_in[5];
    const int*  edge_index = (const int*)d_in[6];
    const int*  e2g        = (const int*)d_in[7];
    const void* W_node     = d_in[8];
    const void* W_time     = d_in[9];
    const void* W_latent   = d_in[10];
    const void* ln_gamma   = d_in[11];
    const void* ln_beta    = d_in[12];
    const void* We1        = d_in[13];
    const void* be1        = d_in[14];
    const void* We2        = d_in[15];
    const void* be2        = d_in[16];
    const void* Wn1        = d_in[17];
    const void* bn1        = d_in[18];
    const void* Wn2        = d_in[19];
    const void* bn2        = d_in[20];
    const void* W_numatom  = d_in[21];
    const void* fln_gamma  = d_in[22];
    const void* fln_beta   = d_in[23];
    const void* W_coord    = d_in[24];
    const void* W_latout   = d_in[25];
    const void* b_latout   = d_in[26];

    // workspace carve (~102 MB)
    char* p = (char*)d_ws;
    auto alloc = [&](size_t bytes) { char* r = p; p += (bytes + 255) & ~(size_t)255; return r; };
    int*   flag  = (int*)alloc(4);
    float* ltl   = (float*)alloc((size_t)B_*9*4);
    float* q     = (float*)alloc((size_t)H_*4);
    float* h     = (float*)alloc((size_t)N_*H_*4);
    int*   edat  = (int*)alloc((size_t)E_*4*4);
    bf16* hnAB  = (bf16*)alloc((size_t)N_*1024*2);
    bf16* femb  = (bf16*)alloc((size_t)E_*KF_*2);
    bf16* e1    = (bf16*)alloc((size_t)E_*H_*2);    // prep-phase alias: PQa
    bf16* e2    = (bf16*)alloc((size_t)E_*H_*2);    // prep-phase alias: PQbt
    bf16* cat   = (bf16*)alloc((size_t)N_*1024*2);
    bf16* n1s   = (bf16*)alloc((size_t)N_*H_*2);
    bf16* PQc   = (bf16*)alloc((size_t)7*128*512*2);
    bf16* WtAB  = (bf16*)alloc((size_t)1024*512*2);
    bf16* Wtf   = (bf16*)alloc((size_t)512*KF_*2);
    bf16* Wte2  = (bf16*)alloc((size_t)512*512*2);
    bf16* Wtn1  = (bf16*)alloc((size_t)512*1024*2);
    bf16* Wtn2  = (bf16*)alloc((size_t)512*512*2);
    bf16* PQa   = e1;
    bf16* PQbt  = e2;

    if ((size_t)(p - (char*)d_ws) > ws_size) {
        ws_sentinel<<<1, 64, 0, stream>>>((bf16*)d_out);
        return;
    }

    // ---- prep
    detect_dtype<<<1, 64, 0, stream>>>((const unsigned int*)t, flag);
    prep_graph<<<1, 64, 0, stream>>>(latp, ltl, flag);
    prep_q<<<1, 512, 0, stream>>>(W_time, W_latent, q, flag);
    pq_gather<<<dim3(7, 16), 256, 0, stream>>>(W_node, W_numatom, PQa, flag);
    transpose_pq<<<dim3(16, 16, 7), dim3(32, 8), 0, stream>>>(W_latent, We1, PQbt, flag);
    gemm_bt<0,128><<<dim3(4, 1, 7), 256, 0, stream>>>(
        PQa, 512, PQbt, nullptr, 0, PQc, nullptr, 512, 512,
        (size_t)128*512, (size_t)512*512, (size_t)128*512,
        flag, nullptr, nullptr, nullptr, 0);
    node_embed_fast<<<N_, 512, 0, stream>>>(PQc, q, t, atom_types, node2graph, h, flag);
    edge_prep<<<E_, 384, 0, stream>>>(frac, edge_index, e2g, latp, num_atoms, ltl, edat, femb, flag);

    // ---- layers
    for (size_t l = 0; l < NL_; l++) {
        transpose_layer<<<dim3(16, 32, 6), dim3(32, 8), 0, stream>>>(
            We1, We2, Wn1, Wn2, l, WtAB, Wtf, Wte2, Wtn1, Wtn2, flag);
        wtf_tail<<<1, 512, 0, stream>>>(We1, l, Wtf, flag);
        ln_kernel<<<N_, 256, 0, stream>>>(h, ln_gamma, ln_beta, l*H_, cat, flag);
        // hnAB = hn @ [WA|WB]
        gemm_bt<0,64><<<dim3(8, N_/64), 256, 0, stream>>>(
            cat, 1024, WtAB, nullptr, 0, hnAB, nullptr, 512, 1024, 0, 0, 0,
            flag, nullptr, nullptr, nullptr, 0);
        // e1 = silu(femb_aug@Wf_aug + hnA[src] + hnB[dst] + Q[na] + be1)
        gemm_bt<3,64><<<dim3(4, E_/64), 256, 0, stream>>>(
            femb, KF_, Wtf, be1, l*H_, e1, nullptr, KF_, 512, 0, 0, 0,
            flag, hnAB, PQc, edat, l);
        // e2 = silu(e1@We2 + be2)
        gemm_bt<1,64><<<dim3(4, E_/64), 256, 0, stream>>>(
            e1, 512, Wte2, be2, l*H_, e2, nullptr, 512, 512, 0, 0, 0,
            flag, nullptr, nullptr, nullptr, 0);
        seg_mean<<<N_, 256, 0, stream>>>(e2, cat);
        // n1s = silu(cat@Wn1 + bn1)
        gemm_bt<1,64><<<dim3(4, N_/64), 256, 0, stream>>>(
            cat, 1024, Wtn1, bn1, l*H_, n1s, nullptr, 1024, 512, 0, 0, 0,
            flag, nullptr, nullptr, nullptr, 0);
        // h += silu(n1s@Wn2 + bn2)
        gemm_bt<2,64><<<dim3(4, N_/64), 256, 0, stream>>>(
            n1s, 512, Wtn2, bn2, l*H_, nullptr, h, 512, 512, 0, 0, 0,
            flag, nullptr, nullptr, nullptr, 0);
    }

    // ---- heads
    ln_kernel<<<N_, 256, 0, stream>>>(h, fln_gamma, fln_beta, 0, cat, flag);
    pos_out<<<N_/4, 256, 0, stream>>>(cat, W_coord, d_out, flag);
    cell_out<<<B_, 512, 0, stream>>>(cat, W_latout, b_latout, num_atoms, d_out, flag);
}

// Round 8
// 1056.873 us; speedup vs baseline: 1.6089x; 1.1254x over previous
//
#include <hip/hip_runtime.h>
#include <hip/hip_bf16.h>

typedef __hip_bfloat16 bf16;
typedef unsigned char u8;
typedef __attribute__((ext_vector_type(8))) __bf16 bf16x8;
typedef __attribute__((ext_vector_type(4))) float f32x4;

#define B_   64
#define NPG_ 20
#define H_   512
#define TD_  256
#define NF_  128
#define NL_  6
#define A_   100
#define N_   (B_ * NPG_)            // 1280
#define E_   (B_ * NPG_ * (NPG_-1)) // 24320
#define EIN_ 2313
#define KF_  832                     // 768 femb + 9 geo + 55 zero-pad

__device__ __forceinline__ float bf2f(bf16 x) { return __bfloat162float(x); }
__device__ __forceinline__ bf16  f2bf(float x) { return __float2bfloat16(x); }
__device__ __forceinline__ float siluf(float x) { return x / (1.0f + expf(-x)); }
__device__ __forceinline__ float ldf(const void* p, size_t i, int isb) {
    return isb ? bf2f(((const bf16*)p)[i]) : ((const float*)p)[i];
}
// manual float -> OCP e4m3fn (round-nearest-even via rintf)
__device__ __forceinline__ u8 f2f8(float f) {
    unsigned s = (__float_as_uint(f) >> 24) & 0x80;
    float a = fabsf(f);
    if (!(a == a)) return (u8)0x7F;
    if (a == 0.0f) return (u8)s;
    if (a >= 448.0f) return (u8)(s | 0x7E);
    int e; float m = frexpf(a, &e);      // a = m*2^e, m in [0.5,1)
    int ef = e + 6;
    unsigned code;
    if (ef >= 1) {
        int mant = (int)rintf(m * 16.0f) - 8;   // 0..8
        if (mant == 8) { mant = 0; ef++; }
        if (ef > 15) return (u8)(s | 0x7E);
        code = ((unsigned)ef << 3) | (unsigned)mant;
    } else {
        int mant = (int)rintf(ldexpf(a, 9));    // subnormal: a/2^-9
        code = (mant >= 8) ? (1u<<3) : (unsigned)mant;
    }
    return (u8)(s | code);
}
// async global->LDS, 16B/lane; lane i scatters to uniform base + i*16
__device__ __forceinline__ void async_cp16(const void* src, void* dst) {
    __builtin_amdgcn_global_load_lds(
        (const __attribute__((address_space(1))) unsigned int*)src,
        (__attribute__((address_space(3))) unsigned int*)dst,
        16, 0, 0);
}

// ---------------------------------------------------------------- dtype detect on t (uniform [0,1))
__global__ void detect_dtype(const unsigned int* __restrict__ tw, int* __restrict__ flag) {
    if (threadIdx.x != 0) return;
    int cnt = 0;
    for (int i = 0; i < 32; i++) {
        unsigned b1 = (tw[i] >> 8) & 0xFF;
        if (b1 >= 0x20 && b1 < 0x40) cnt++;
    }
    *flag = (cnt >= 16) ? 1 : 0;
}

__global__ void ws_sentinel(bf16* out) { if (threadIdx.x == 0) out[0] = f2bf(1000.0f); }

// ---------------------------------------------------------------- prep: lattice -> ltl (B,3,3)
__global__ void prep_graph(const void* __restrict__ latp, float* __restrict__ ltl,
                           const int* __restrict__ flag) {
    int b = threadIdx.x;
    if (b >= B_) return;
    int isb = *flag;
    const float LM[3] = {1.575442910194397f, 1.7017393112182617f, 1.9781638383865356f};
    const float LS[3] = {0.24437622725963593f, 0.26526379585266113f, 0.3535512685775757f};
    float lp[6];
    for (int i = 0; i < 6; i++) lp[i] = ldf(latp, b*6 + i, isb);
    float len[3], c[3], s[3];
    for (int i = 0; i < 3; i++) len[i] = expf(lp[i] * LS[i] + LM[i]);
    for (int i = 0; i < 3; i++) {
        float sig = 1.0f / (1.0f + expf(-lp[3+i]));
        float deg = 59.9f + 60.2f * sig;
        float a = deg * 0.017453292519943295f;
        c[i] = cosf(a); s[i] = sinf(a);
    }
    float val = (c[0]*c[1] - c[2]) / (s[0]*s[1]);
    val = fminf(1.0f, fmaxf(-1.0f, val));
    float gs = acosf(val);
    float L[3][3];
    L[0][0] = len[0]*s[1]; L[0][1] = 0.0f;               L[0][2] = len[0]*c[1];
    L[1][0] = -len[1]*s[0]*cosf(gs); L[1][1] = len[1]*s[0]*sinf(gs); L[1][2] = len[1]*c[0];
    L[2][0] = 0.0f; L[2][1] = 0.0f; L[2][2] = len[2];
    for (int i = 0; i < 3; i++)
        for (int k = 0; k < 3; k++)
            ltl[b*9 + i*3 + k] = L[i][0]*L[k][0] + L[i][1]*L[k][1] + L[i][2]*L[k][2];
}

// ---------------------------------------------------------------- prep: q[j] = sum_d W_time[d]*W_latent[512+d][j]
__global__ __launch_bounds__(512) void prep_q(const void* __restrict__ W_time,
                                              const void* __restrict__ W_latent,
                                              float* __restrict__ q,
                                              const int* __restrict__ flag) {
    int j = threadIdx.x;
    int isb = *flag;
    float s0 = 0.0f, s1 = 0.0f, s2 = 0.0f, s3 = 0.0f;
    for (int d = 0; d < TD_; d += 4) {
        s0 += ldf(W_time, d+0, isb) * ldf(W_latent, (size_t)(H_ + d+0)*H_ + j, isb);
        s1 += ldf(W_time, d+1, isb) * ldf(W_latent, (size_t)(H_ + d+1)*H_ + j, isb);
        s2 += ldf(W_time, d+2, isb) * ldf(W_latent, (size_t)(H_ + d+2)*H_ + j, isb);
        s3 += ldf(W_time, d+3, isb) * ldf(W_latent, (size_t)(H_ + d+3)*H_ + j, isb);
    }
    q[j] = (s0 + s1) + (s2 + s3);
}

// ---------------------------------------------------------------- gather A rows for PQ gemm (7 slots of 128x512)
__global__ __launch_bounds__(256) void pq_gather(const void* __restrict__ W_node,
                                                 const void* __restrict__ W_numatom,
                                                 bf16* __restrict__ PQa,
                                                 const int* __restrict__ flag) {
    int z = blockIdx.x, ch = blockIdx.y;
    int isb = *flag;
    int base = ch * 4096;
    for (int idx = base + threadIdx.x; idx < base + 4096; idx += 256) {
        int r = idx >> 9, c = idx & 511;
        float v = 0.0f;
        if (r < A_) {
            if (z == 0) v = ldf(W_node, (size_t)r*512 + c, isb);
            else        v = ldf(W_numatom, ((size_t)(z-1)*A_ + r)*512 + c, isb);
        }
        PQa[(size_t)z*65536 + idx] = f2bf(v);
    }
}

// ---------------------------------------------------------------- transpose for PQ Bt (7 slots of 512x512)
__global__ __launch_bounds__(256) void transpose_pq(const void* __restrict__ W_latent,
                                                    const void* __restrict__ We1,
                                                    bf16* __restrict__ PQbt,
                                                    const int* __restrict__ flag) {
    __shared__ bf16 tile[32][33];
    int z = blockIdx.z;
    int isb = *flag;
    const void* src = (z == 0) ? W_latent : We1;
    size_t off = (z == 0) ? 0 : ((size_t)(z-1)*EIN_ + 1801)*512;
    bf16* dst = PQbt + (size_t)z*512*512;
    int r0 = blockIdx.y * 32, c0 = blockIdx.x * 32;
    #pragma unroll
    for (int i = 0; i < 32; i += 8)
        tile[threadIdx.y + i][threadIdx.x] =
            f2bf(ldf(src, off + (size_t)(r0 + threadIdx.y + i)*512 + c0 + threadIdx.x, isb));
    __syncthreads();
    #pragma unroll
    for (int i = 0; i < 32; i += 8)
        dst[(size_t)(c0 + threadIdx.y + i)*512 + r0 + threadIdx.x] = tile[threadIdx.x][threadIdx.y + i];
}

// ---------------------------------------------------------------- weight transpose; z = lz*6 + which
// which 2 (Wtf) writes fp8 with row stride KF_; others bf16
__global__ __launch_bounds__(256) void transpose_layer(
    const void* __restrict__ We1p, const void* __restrict__ We2p,
    const void* __restrict__ Wn1p, const void* __restrict__ Wn2p, size_t l0, int allmode,
    bf16* __restrict__ WtAB, u8* __restrict__ Wtf8, bf16* __restrict__ Wte2,
    bf16* __restrict__ Wtn1, bf16* __restrict__ Wtn2,
    const int* __restrict__ flag) {
    __shared__ bf16 tile[32][33];
    int which = blockIdx.z % 6;
    size_t lz = blockIdx.z / 6;
    size_t l = l0 + lz, lw = allmode ? lz : 0;
    int isb = *flag;
    const void* src; size_t off; bf16* dst = nullptr; int R; int ldd;
    switch (which) {
        case 0:  src = We1p; off = (l*EIN_ + 3)*512;    dst = WtAB + lw*512*1024;            R = 512;  ldd = 512;  break;
        case 1:  src = We1p; off = (l*EIN_ + 515)*512;  dst = WtAB + lw*512*1024 + 512*512;  R = 512;  ldd = 512;  break;
        case 2:  src = We1p; off = (l*EIN_ + 1033)*512; R = 768; ldd = KF_; break;
        case 3:  src = We2p; off = l*512*512;           dst = Wte2 + lw*512*512;             R = 512;  ldd = 512;  break;
        case 4:  src = Wn1p; off = l*1024*512;          dst = Wtn1 + lw*512*1024;            R = 1024; ldd = 1024; break;
        default: src = Wn2p; off = l*512*512;           dst = Wtn2 + lw*512*512;             R = 512;  ldd = 512;  break;
    }
    int r0 = blockIdx.y * 32, c0 = blockIdx.x * 32;
    if (r0 >= R) return;
    #pragma unroll
    for (int i = 0; i < 32; i += 8)
        tile[threadIdx.y + i][threadIdx.x] =
            f2bf(ldf(src, off + (size_t)(r0 + threadIdx.y + i)*512 + c0 + threadIdx.x, isb));
    __syncthreads();
    if (which == 2) {
        u8* d8 = Wtf8 + lw*(size_t)512*KF_;
        #pragma unroll
        for (int i = 0; i < 32; i += 8)
            d8[(size_t)(c0 + threadIdx.y + i)*KF_ + r0 + threadIdx.x] =
                f2f8(bf2f(tile[threadIdx.x][threadIdx.y + i]));
    } else {
        #pragma unroll
        for (int i = 0; i < 32; i += 8)
            dst[(size_t)(c0 + threadIdx.y + i)*ldd + r0 + threadIdx.x] = tile[threadIdx.x][threadIdx.y + i];
    }
}

// ---------------------------------------------------------------- Wtf8 tail cols 768..831: 9 geometry rows of We1
__global__ __launch_bounds__(512) void wtf_tail(const void* __restrict__ We1, size_t l0, int allmode,
                                                u8* __restrict__ Wtf8,
                                                const int* __restrict__ flag) {
    size_t lz = blockIdx.x;
    size_t l = l0 + lz, lw = allmode ? lz : 0;
    int n = threadIdx.x;
    int isb = *flag;
    const int rows[9] = {0, 1, 2, 1027, 1028, 1029, 1030, 1031, 1032};
    u8* d8 = Wtf8 + lw*(size_t)512*KF_;
    #pragma unroll
    for (int j = 0; j < 64; j++) {
        float v = (j < 9) ? ldf(We1, (l*EIN_ + rows[j])*512 + n, isb) : 0.0f;
        d8[(size_t)n*KF_ + 768 + j] = f2f8(v);
    }
}

// ---------------------------------------------------------------- cbias[l][g][j] = be1[l][j] + Qc[1+l][na_g][j]
__global__ __launch_bounds__(512) void cbias_prep(const bf16* __restrict__ PQc,
                                                  const void* __restrict__ be1,
                                                  const int* __restrict__ num_atoms,
                                                  float* __restrict__ cbias,
                                                  const int* __restrict__ flag) {
    int l = blockIdx.x, g = blockIdx.y, j = threadIdx.x;
    int isb = *flag;
    int na = num_atoms[g] - 1;
    float qv = (na >= 0 && na < A_) ? bf2f(PQc[(size_t)(1+l)*65536 + (size_t)na*512 + j]) : 0.0f;
    cbias[((size_t)l*B_ + g)*512 + j] = ldf(be1, l*512 + j, isb) + qv;
}

// ---------------------------------------------------------------- node embed: h[i][j] = P[at_i][j] + t[g]*q[j]
__global__ __launch_bounds__(512) void node_embed_fast(const bf16* __restrict__ P,
                                                       const float* __restrict__ q,
                                                       const void* __restrict__ t,
                                                       const int* __restrict__ atom_types,
                                                       const int* __restrict__ node2graph,
                                                       float* __restrict__ h,
                                                       const int* __restrict__ flag) {
    int i = blockIdx.x, j = threadIdx.x;
    int isb = *flag;
    int at = atom_types[i] - 1; if (at < 0) at = 0;
    float pv = (at < A_) ? bf2f(P[(size_t)at*512 + j]) : 0.0f;
    float tv = ldf(t, node2graph[i], isb);
    h[(size_t)i*H_ + j] = pv + tv * q[j];
}

// ---------------------------------------------------------------- edge prep: femb8(E x 832 fp8) + edat[E][4] = (src,dst,g,0)
__global__ __launch_bounds__(384) void edge_prep(const void* __restrict__ frac,
                                                 const int* __restrict__ edge_index,
                                                 const int* __restrict__ e2g,
                                                 const void* __restrict__ latp,
                                                 const float* __restrict__ ltl,
                                                 int* __restrict__ edat,
                                                 u8* __restrict__ femb8,
                                                 const int* __restrict__ flag) {
    const float TWO_PI_F = 6.283185307179586f;
    int e = blockIdx.x;
    int isb = *flag;
    int src = edge_index[e], dst = edge_index[E_ + e];
    int tid = threadIdx.x;
    int d = tid >> 7, k = tid & 127;
    float x = ldf(frac, src*3 + d, isb), y = ldf(frac, dst*3 + d, isb);
    float diff = y - x;
    float fd = diff - rintf(diff);
    float sv, cv;
    sincosf(fd * (TWO_PI_F * (float)k), &sv, &cv);
    femb8[(size_t)e*KF_ + d*NF_ + k]       = f2f8(sv);
    femb8[(size_t)e*KF_ + 384 + d*NF_ + k] = f2f8(cv);
    if (tid < 64) {
        int g = e2g[e];
        float v = 0.0f;
        if (tid < 3) {
            float f3[3];
            for (int dd = 0; dd < 3; dd++) {
                float df = ldf(frac, dst*3 + dd, isb) - ldf(frac, src*3 + dd, isb);
                f3[dd] = df - rintf(df);
            }
            float dots[3];
            for (int i = 0; i < 3; i++)
                dots[i] = ltl[g*9 + i*3 + 0]*f3[0] + ltl[g*9 + i*3 + 1]*f3[1] + ltl[g*9 + i*3 + 2]*f3[2];
            float nrm = sqrtf(dots[0]*dots[0] + dots[1]*dots[1] + dots[2]*dots[2]);
            v = dots[tid] / (nrm + 1e-12f);
        } else if (tid < 9) {
            v = ldf(latp, g*6 + tid - 3, isb);
        }
        femb8[(size_t)e*KF_ + 768 + tid] = f2f8(v);
        if (tid == 0) {
            edat[e*4 + 0] = src;
            edat[e*4 + 1] = dst;
            edat[e*4 + 2] = g;
            edat[e*4 + 3] = 0;
        }
    }
}

// ---------------------------------------------------------------- layernorm over H=512 -> cat[:, :512] (stride 1024)
__device__ __forceinline__ float block_sum_256(float v, float* red) {
    for (int o = 32; o; o >>= 1) v += __shfl_down(v, o);
    int w = threadIdx.x >> 6, lane = threadIdx.x & 63;
    if (lane == 0) red[w] = v;
    __syncthreads();
    float s = red[0] + red[1] + red[2] + red[3];
    __syncthreads();
    return s;
}

__global__ __launch_bounds__(256) void ln_kernel(const float* __restrict__ x,
                                                 const void* __restrict__ gamma,
                                                 const void* __restrict__ beta, size_t goff,
                                                 bf16* __restrict__ cat,
                                                 const int* __restrict__ flag) {
    __shared__ float red[4];
    size_t n = blockIdx.x;
    int tid = threadIdx.x;
    int isb = *flag;
    const float* xr = x + n*H_;
    float v0 = xr[tid], v1 = xr[tid + 256];
    float mu = block_sum_256(v0 + v1, red) * (1.0f/512.0f);
    float d0 = v0 - mu, d1 = v1 - mu;
    float var = block_sum_256(d0*d0 + d1*d1, red) * (1.0f/512.0f);
    float rs = 1.0f / sqrtf(var + 1e-5f);
    cat[n*1024 + tid]       = f2bf(d0*rs*ldf(gamma, goff + tid, isb)       + ldf(beta, goff + tid, isb));
    cat[n*1024 + 256 + tid] = f2bf(d1*rs*ldf(gamma, goff + tid + 256, isb) + ldf(beta, goff + tid + 256, isb));
}

// ---------------------------------------------------------------- bf16 MFMA GEMM (EPI 0/1/2), BK=64, async+XOR swizzle
template<int EPI, int TM>
__global__ __launch_bounds__(256) void gemm_bt(
        const bf16* __restrict__ A, int lda,
        const bf16* __restrict__ Bt,
        const void* __restrict__ bias, size_t boff,
        bf16* __restrict__ Cb, float* __restrict__ Cf,
        int K, int N,
        size_t zsA, size_t zsB, size_t zsC,
        const int* __restrict__ flag) {
    constexpr int MT = TM / 32;
    __shared__ __align__(16) bf16 As[TM*64];
    __shared__ __align__(16) bf16 Bs[128*64];
    const int z = blockIdx.z;
    A  += (size_t)z * zsA;
    Bt += (size_t)z * zsB;
    const size_t coff = (size_t)z * zsC;
    const int tid = threadIdx.x;
    const int wave = tid >> 6, lane = tid & 63;
    const int lrow = lane & 15, lq = lane >> 4;
    const size_t m0 = (size_t)blockIdx.y * TM;
    const int n0 = blockIdx.x * 128;
    const int wm = (wave >> 1) * (TM/2), wn = (wave & 1) * 64;
    const int ar = lane >> 3;
    const int gk = (lane & 7) ^ ar;
    f32x4 acc[MT][4] = {};

    for (int k0 = 0; k0 < K; k0 += 64) {
        if (k0) __syncthreads();
        #pragma unroll
        for (int i = 0; i < TM/32; i++) {
            int R = wave*(TM/4) + i*8;
            async_cp16(A + (m0 + R + ar)*lda + k0 + gk*8, As + R*64);
        }
        #pragma unroll
        for (int i = 0; i < 4; i++) {
            int R = wave*32 + i*8;
            async_cp16(Bt + (size_t)(n0 + R + ar)*K + k0 + gk*8, Bs + R*64);
        }
        __syncthreads();
        #pragma unroll
        for (int kk = 0; kk < 2; kk++) {
            bf16x8 af[MT], bfr[4];
            #pragma unroll
            for (int mt = 0; mt < MT; mt++) {
                int r = wm + mt*16 + lrow;
                int p = (kk*4 + lq) ^ (r & 7);
                af[mt] = *(const bf16x8*)(As + r*64 + p*8);
            }
            #pragma unroll
            for (int nt = 0; nt < 4; nt++) {
                int r = wn + nt*16 + lrow;
                int p = (kk*4 + lq) ^ (r & 7);
                bfr[nt] = *(const bf16x8*)(Bs + r*64 + p*8);
            }
            #pragma unroll
            for (int mt = 0; mt < MT; mt++)
                #pragma unroll
                for (int nt = 0; nt < 4; nt++)
                    acc[mt][nt] = __builtin_amdgcn_mfma_f32_16x16x32_bf16(af[mt], bfr[nt], acc[mt][nt], 0, 0, 0);
        }
    }

    const int isb = bias ? *flag : 0;
    #pragma unroll
    for (int mt = 0; mt < MT; mt++)
        #pragma unroll
        for (int nt = 0; nt < 4; nt++) {
            int col = n0 + wn + nt*16 + lrow;
            float bv = bias ? ldf(bias, boff + col, isb) : 0.0f;
            #pragma unroll
            for (int r = 0; r < 4; r++) {
                size_t row = m0 + wm + mt*16 + lq*4 + r;
                float x = acc[mt][nt][r] + bv;
                if (EPI == 0)      Cb[coff + row*N + col] = f2bf(x);
                else if (EPI == 1) Cb[coff + row*N + col] = f2bf(siluf(x));
                else               Cf[coff + row*N + col] += siluf(x);
            }
        }
}

// ---------------------------------------------------------------- fp8 e1 GEMM: e1 = silu(femb8 @ Wtf8^T + cbias[g] + hnA[src] + hnB[dst])
// TM=64, BN=128, BK=64 (fp8 bytes). Staging 16-row windows (ar=lane>>2, ac=lane&3),
// XOR swizzle over 4x16B chunks: physical p = logical c ^ (r&3).
__global__ __launch_bounds__(256) void gemm_fp8_e1(
        const u8* __restrict__ A,           // E x 832
        const u8* __restrict__ Bt,          // 512 x 832
        const float* __restrict__ cbias_l,  // B x 512
        const bf16* __restrict__ hnAB,
        const int* __restrict__ edat,
        bf16* __restrict__ Cb) {
    __shared__ __align__(16) u8 As[64*64];
    __shared__ __align__(16) u8 Bs[128*64];
    const int tid = threadIdx.x;
    const int wave = tid >> 6, lane = tid & 63;
    const int lrow = lane & 15, lq = lane >> 4;
    const size_t m0 = (size_t)blockIdx.y * 64;
    const int n0 = blockIdx.x * 128;
    const int wm = (wave >> 1) * 32, wn = (wave & 1) * 64;
    const int ar = lane >> 2;          // row in 16-row window
    const int ac = lane & 3;           // 16B chunk slot
    const int gk = ac ^ (ar & 3);      // global chunk fetched
    f32x4 acc[2][4] = {};

    for (int k0 = 0; k0 < KF_; k0 += 64) {
        if (k0) __syncthreads();
        {   // A: 4 windows of 16 rows, one per wave
            int R = wave*16;
            async_cp16(A + (m0 + R + ar)*KF_ + k0 + gk*16, As + R*64);
        }
        #pragma unroll
        for (int i = 0; i < 2; i++) {   // B: 8 windows, two per wave
            int R = wave*32 + i*16;
            async_cp16(Bt + (size_t)(n0 + R + ar)*KF_ + k0 + gk*16, Bs + R*64);
        }
        __syncthreads();
        #pragma unroll
        for (int kk = 0; kk < 2; kk++) {
            long long af[2], bfr[4];
            #pragma unroll
            for (int mt = 0; mt < 2; mt++) {
                int r = wm + mt*16 + lrow;
                int p = (kk*2 + (lq >> 1)) ^ (r & 3);
                af[mt] = *(const long long*)(As + r*64 + p*16 + (lq & 1)*8);
            }
            #pragma unroll
            for (int nt = 0; nt < 4; nt++) {
                int r = wn + nt*16 + lrow;
                int p = (kk*2 + (lq >> 1)) ^ (r & 3);
                bfr[nt] = *(const long long*)(Bs + r*64 + p*16 + (lq & 1)*8);
            }
            #pragma unroll
            for (int mt = 0; mt < 2; mt++)
                #pragma unroll
                for (int nt = 0; nt < 4; nt++)
                    acc[mt][nt] = __builtin_amdgcn_mfma_f32_16x16x32_fp8_fp8(af[mt], bfr[nt], acc[mt][nt], 0, 0, 0);
        }
    }

    #pragma unroll
    for (int mt = 0; mt < 2; mt++) {
        #pragma unroll
        for (int r = 0; r < 4; r++) {
            size_t e = m0 + wm + mt*16 + lq*4 + r;
            const int4 q = *(const int4*)(edat + e*4);
            int se = q.x, de = q.y, g = q.z;
            #pragma unroll
            for (int nt = 0; nt < 4; nt++) {
                int col = n0 + wn + nt*16 + lrow;
                float x = acc[mt][nt][r]
                        + cbias_l[(size_t)g*512 + col]
                        + bf2f(hnAB[(size_t)se*1024 + col])
                        + bf2f(hnAB[(size_t)de*1024 + 512 + col]);
                Cb[e*512 + col] = f2bf(siluf(x));
            }
        }
    }
}

// ---------------------------------------------------------------- agg: mean over each node's 19 contiguous edges
__global__ __launch_bounds__(256) void seg_mean(const bf16* __restrict__ e2,
                                                bf16* __restrict__ cat) {
    int n = blockIdx.x;
    #pragma unroll
    for (int jj = 0; jj < 2; jj++) {
        int j = threadIdx.x + jj*256;
        const bf16* base = e2 + (size_t)n*19*H_ + j;
        float s = 0.0f;
        #pragma unroll
        for (int i = 0; i < 19; i++) s += bf2f(base[(size_t)i*H_]);
        cat[(size_t)n*1024 + 512 + j] = f2bf(s / 19.0f);
    }
}

// ---------------------------------------------------------------- heads (hln lives in cat[:, :512], stride 1024)
__global__ __launch_bounds__(256) void pos_out(const bf16* __restrict__ hln,
                                               const void* __restrict__ W_coord,
                                               void* __restrict__ out,
                                               const int* __restrict__ flag) {
    int wave = threadIdx.x >> 6, lane = threadIdx.x & 63;
    int n = blockIdx.x*4 + wave;
    int isb = *flag;
    float s0 = 0, s1 = 0, s2 = 0;
    for (int k = lane; k < H_; k += 64) {
        float hv = bf2f(hln[(size_t)n*1024 + k]);
        s0 += hv * ldf(W_coord, k*3 + 0, isb);
        s1 += hv * ldf(W_coord, k*3 + 1, isb);
        s2 += hv * ldf(W_coord, k*3 + 2, isb);
    }
    for (int o = 32; o; o >>= 1) {
        s0 += __shfl_down(s0, o); s1 += __shfl_down(s1, o); s2 += __shfl_down(s2, o);
    }
    if (lane == 0) {
        if (isb) { bf16* o = (bf16*)out;  o[n*3] = f2bf(s0); o[n*3+1] = f2bf(s1); o[n*3+2] = f2bf(s2); }
        else     { float* o = (float*)out; o[n*3] = s0; o[n*3+1] = s1; o[n*3+2] = s2; }
    }
}

__global__ __launch_bounds__(512) void cell_out(const bf16* __restrict__ hln,
                                                const void* __restrict__ W_latout,
                                                const void* __restrict__ b_latout,
                                                const int* __restrict__ num_atoms,
                                                void* __restrict__ out,
                                                const int* __restrict__ flag) {
    __shared__ float red[8*6];
    int b = blockIdx.x, j = threadIdx.x;
    int isb = *flag;
    float s = 0.0f;
    for (int i = 0; i < NPG_; i++) s += bf2f(hln[(size_t)(b*NPG_ + i)*1024 + j]);
    float m = s / (float)num_atoms[b];
    float p[6];
    #pragma unroll
    for (int c = 0; c < 6; c++)
        p[c] = m * ldf(W_latout, j*6 + c, isb) + s * ldf(W_latout, (512 + j)*6 + c, isb);
    int w = j >> 6, lane = j & 63;
    #pragma unroll
    for (int c = 0; c < 6; c++) {
        float v = p[c];
        for (int o = 32; o; o >>= 1) v += __shfl_down(v, o);
        if (lane == 0) red[w*6 + c] = v;
    }
    __syncthreads();
    if (j < 6) {
        float v = 0.0f;
        for (int w2 = 0; w2 < 8; w2++) v += red[w2*6 + j];
        float r = v + ldf(b_latout, j, isb);
        if (isb) ((bf16*)out)[N_*3 + b*6 + j] = f2bf(r);
        else     ((float*)out)[N_*3 + b*6 + j] = r;
    }
}

// ================================================================ host
extern "C" void kernel_launch(void* const* d_in, const int* in_sizes, int n_in,
                              void* d_out, int out_size, void* d_ws, size_t ws_size,
                              hipStream_t stream) {
    const void* t          = d_in[0];
    const void* frac       = d_in[1];
    const void* latp       = d_in[2];
    const int*  atom_types = (const int*)d_in[3];
    const int*  num_atoms  = (const int*)d_in[4];
    const int*  node2graph = (const int*)d_in[5];
    const int*  edge_index = (const int*)d_in[6];
    const int*  e2g        = (const int*)d_in[7];
    const void* W_node     = d_in[8];
    const void* W_time     = d_in[9];
    const void* W_latent   = d_in[10];
    const void* ln_gamma   = d_in[11];
    const void* ln_beta    = d_in[12];
    const void* We1        = d_in[13];
    const void* be1        = d_in[14];
    const void* We2        = d_in[15];
    const void* be2        = d_in[16];
    const void* Wn1        = d_in[17];
    const void* bn1        = d_in[18];
    const void* Wn2        = d_in[19];
    const void* bn2        = d_in[20];
    const void* W_numatom  = d_in[21];
    const void* fln_gamma  = d_in[22];
    const void* fln_beta   = d_in[23];
    const void* W_coord    = d_in[24];
    const void* W_latout   = d_in[25];
    const void* b_latout   = d_in[26];

    // decide whether all-layer weight transposes fit (host-side, deterministic per ws_size)
    const size_t fixed =
        256 + ((size_t)B_*9*4 + 255 & ~255ull) + 2048 + (size_t)N_*H_*4 + (size_t)E_*16
        + (size_t)N_*1024*2 + (size_t)E_*KF_ + (size_t)E_*H_*2*2 + (size_t)N_*1024*2
        + (size_t)N_*H_*2 + (size_t)7*128*512*2 + (size_t)NL_*B_*512*4 + 8192;
    const size_t perlayer_w = (size_t)512*1024*2 + (size_t)512*KF_ + (size_t)512*512*2
                            + (size_t)512*1024*2 + (size_t)512*512*2 + 2048;
    int allmode = (fixed + 6*perlayer_w <= ws_size) ? 1 : 0;
    size_t nw = allmode ? 6 : 1;

    char* p = (char*)d_ws;
    auto alloc = [&](size_t bytes) { char* r = p; p += (bytes + 255) & ~(size_t)255; return r; };
    int*   flag  = (int*)alloc(4);
    float* ltl   = (float*)alloc((size_t)B_*9*4);
    float* q     = (float*)alloc((size_t)H_*4);
    float* h     = (float*)alloc((size_t)N_*H_*4);
    int*   edat  = (int*)alloc((size_t)E_*4*4);
    bf16* hnAB  = (bf16*)alloc((size_t)N_*1024*2);
    u8*   femb8 = (u8*)alloc((size_t)E_*KF_);
    bf16* e1    = (bf16*)alloc((size_t)E_*H_*2);    // prep-phase alias: PQa
    bf16* e2    = (bf16*)alloc((size_t)E_*H_*2);    // prep-phase alias: PQbt
    bf16* cat   = (bf16*)alloc((size_t)N_*1024*2);
    bf16* n1s   = (bf16*)alloc((size_t)N_*H_*2);
    bf16* PQc   = (bf16*)alloc((size_t)7*128*512*2);
    float* cbias = (float*)alloc((size_t)NL_*B_*512*4);
    bf16* WtAB  = (bf16*)alloc(nw*(size_t)512*1024*2);
    u8*   Wtf8  = (u8*)alloc(nw*(size_t)512*KF_);
    bf16* Wte2  = (bf16*)alloc(nw*(size_t)512*512*2);
    bf16* Wtn1  = (bf16*)alloc(nw*(size_t)512*1024*2);
    bf16* Wtn2  = (bf16*)alloc(nw*(size_t)512*512*2);
    bf16* PQa   = e1;
    bf16* PQbt  = e2;

    if ((size_t)(p - (char*)d_ws) > ws_size) {
        ws_sentinel<<<1, 64, 0, stream>>>((bf16*)d_out);
        return;
    }

    // ---- prep
    detect_dtype<<<1, 64, 0, stream>>>((const unsigned int*)t, flag);
    prep_graph<<<1, 64, 0, stream>>>(latp, ltl, flag);
    prep_q<<<1, 512, 0, stream>>>(W_time, W_latent, q, flag);
    pq_gather<<<dim3(7, 16), 256, 0, stream>>>(W_node, W_numatom, PQa, flag);
    transpose_pq<<<dim3(16, 16, 7), dim3(32, 8), 0, stream>>>(W_latent, We1, PQbt, flag);
    gemm_bt<0,128><<<dim3(4, 1, 7), 256, 0, stream>>>(
        PQa, 512, PQbt, nullptr, 0, PQc, nullptr, 512, 512,
        (size_t)128*512, (size_t)512*512, (size_t)128*512, flag);
    cbias_prep<<<dim3(NL_, B_), 512, 0, stream>>>(PQc, be1, num_atoms, cbias, flag);
    node_embed_fast<<<N_, 512, 0, stream>>>(PQc, q, t, atom_types, node2graph, h, flag);
    edge_prep<<<E_, 384, 0, stream>>>(frac, edge_index, e2g, latp, ltl, edat, femb8, flag);

    if (allmode) {
        transpose_layer<<<dim3(16, 32, 36), dim3(32, 8), 0, stream>>>(
            We1, We2, Wn1, Wn2, 0, 1, WtAB, Wtf8, Wte2, Wtn1, Wtn2, flag);
        wtf_tail<<<6, 512, 0, stream>>>(We1, 0, 1, Wtf8, flag);
    }

    // ---- layers
    for (size_t l = 0; l < NL_; l++) {
        size_t lw = allmode ? l : 0;
        bf16* WtABl = WtAB + lw*512*1024;
        u8*   Wtf8l = Wtf8 + lw*(size_t)512*KF_;
        bf16* Wte2l = Wte2 + lw*512*512;
        bf16* Wtn1l = Wtn1 + lw*512*1024;
        bf16* Wtn2l = Wtn2 + lw*512*512;
        if (!allmode) {
            transpose_layer<<<dim3(16, 32, 6), dim3(32, 8), 0, stream>>>(
                We1, We2, Wn1, Wn2, l, 0, WtAB, Wtf8, Wte2, Wtn1, Wtn2, flag);
            wtf_tail<<<1, 512, 0, stream>>>(We1, l, 0, Wtf8, flag);
        }
        ln_kernel<<<N_, 256, 0, stream>>>(h, ln_gamma, ln_beta, l*H_, cat, flag);
        // hnAB = hn @ [WA|WB]
        gemm_bt<0,64><<<dim3(8, N_/64), 256, 0, stream>>>(
            cat, 1024, WtABl, nullptr, 0, hnAB, nullptr, 512, 1024, 0, 0, 0, flag);
        // e1 = silu(femb8 @ Wtf8 + cbias[g] + hnA[src] + hnB[dst])   [fp8 MFMA]
        gemm_fp8_e1<<<dim3(4, E_/64), 256, 0, stream>>>(
            femb8, Wtf8l, cbias + l*B_*512, hnAB, edat, e1);
        // e2 = silu(e1@We2 + be2)
        gemm_bt<1,64><<<dim3(4, E_/64), 256, 0, stream>>>(
            e1, 512, Wte2l, be2, l*H_, e2, nullptr, 512, 512, 0, 0, 0, flag);
        seg_mean<<<N_, 256, 0, stream>>>(e2, cat);
        // n1s = silu(cat@Wn1 + bn1)
        gemm_bt<1,64><<<dim3(4, N_/64), 256, 0, stream>>>(
            cat, 1024, Wtn1l, bn1, l*H_, n1s, nullptr, 1024, 512, 0, 0, 0, flag);
        // h += silu(n1s@Wn2 + bn2)
        gemm_bt<2,64><<<dim3(4, N_/64), 256, 0, stream>>>(
            n1s, 512, Wtn2l, bn2, l*H_, nullptr, h, 512, 512, 0, 0, 0, flag);
    }

    // ---- heads
    ln_kernel<<<N_, 256, 0, stream>>>(h, fln_gamma, fln_beta, 0, cat, flag);
    pos_out<<<N_/4, 256, 0, stream>>>(cat, W_coord, d_out, flag);
    cell_out<<<B_, 512, 0, stream>>>(cat, W_latout, b_latout, num_atoms, d_out, flag);
}